// Round 1
// baseline (583.688 us; speedup 1.0000x reference)
//
#include <hip/hip_runtime.h>
#include <cmath>

struct K32 { float k[32]; };
struct K16 { float k[16]; };

#define THETA 10.0f

// ====== L1 FUSED: conv1 + psp1(commuted) + spike1 + pool(+psp2 commuted) + spike2 ======
// Reference: spike(pool(psp(spike(conv(psp(x)))))).  psp commutes with conv and pool:
//   spike(psp(pool(spike(psp(conv(x)))))) -- conv on RAW binary spikes, FIR on conv
//   output rows (128/block), spike, pool-sum, FIR on 32 pooled rows, spike, store.
template <int CIN, int COUT, int KK, int HIN, int WIN, int S1H, int S1W,
          int S2H, int S2W>
__global__ __launch_bounds__(256)
void conv_pps_kernel(const float* __restrict__ x, const float* __restrict__ w,
                     float* __restrict__ s2out, K32 pk, K16 rk) {
  constexpr int WT = 4;                       // s1-wo per wave
  constexpr int SW = 8;                       // s1-wo per block
  constexpr int XR = 2 * (WT - 1) + KK;       // 11
  constexpr int GROUPS = (S1W + SW - 1) / SW; // 16
  constexpr int NROW = COUT * 2 * SW;         // 128
  __shared__ float lds[NROW * 51];            // 26 KB
  const int tid = threadIdx.x;
  const int wave = tid >> 6;
  const int lane = tid & 63;
  const int group = blockIdx.x % GROUPS;
  const int rest = blockIdx.x / GROUPS;
  const int hop = rest % S2H;                 // s2 ho
  const int n = rest / S2H;
  const int ho_off = wave & 1;
  const int wo_half = wave >> 1;
  const int ho = 2 * hop + ho_off;            // s1 ho
  const int wo0 = group * SW + wo_half * WT;
  const int tt = lane < 50 ? lane : 49;

  // ---- conv on raw binary input (proven order c -> kh -> co -> kw -> wl) ----
  float acc[COUT][WT] = {};
  for (int c = 0; c < CIN; ++c) {
#pragma unroll
    for (int kh = 0; kh < KK; ++kh) {
      const int hi = 2 * ho + kh - 1;
      if ((unsigned)hi >= (unsigned)HIN) continue;   // zero padding
      float xr[XR];
#pragma unroll
      for (int i = 0; i < XR; ++i) {
        const int wi = 2 * wo0 - 1 + i;
        xr[i] = ((unsigned)wi < (unsigned)WIN)
                    ? x[(((size_t)(n * CIN + c) * HIN + hi) * WIN + wi) * 50 + tt]
                    : 0.f;
      }
#pragma unroll
      for (int co = 0; co < COUT; ++co)
#pragma unroll
        for (int kw = 0; kw < KK; ++kw) {
          const float wv = w[((co * CIN + c) * KK + kh) * KK + kw];
#pragma unroll
          for (int wl = 0; wl < WT; ++wl)
            acc[co][wl] += xr[2 * wl + kw] * wv;
        }
    }
  }
  // ---- transpose: LDS row = co*16 + ho_off*8 + wol ----
  if (lane < 50) {
#pragma unroll
    for (int co = 0; co < COUT; ++co)
#pragma unroll
      for (int wl = 0; wl < WT; ++wl)
        lds[((co * 2 + ho_off) * SW + wo_half * WT + wl) * 51 + lane] = acc[co][wl];
  }
  __syncthreads();
  // ---- FIR1 = psp1 (commuted past conv): 2 threads/row, snapshot -> barrier -> in-place ----
  {
    const int r = tid & (NROW - 1);
    const int part = tid >> 7;
    const int wol = r & (SW - 1);
    const bool act = (group * SW + wol) < S1W;
    float xs[50];
    if (act) {
      if (part == 0) {
#pragma unroll
        for (int t = 0; t < 25; ++t) xs[t] = lds[r * 51 + t];
      } else {
#pragma unroll
        for (int t = 0; t < 50; ++t) xs[t] = lds[r * 51 + t];
      }
    }
    __syncthreads();
    if (act) {
      if (part == 0) {
#pragma unroll
        for (int t = 0; t < 25; ++t) {
          float a = 0.f;
#pragma unroll
          for (int k = 31; k >= 0; --k)
            if (t - k >= 0) a += xs[t - k] * pk.k[k];
          lds[r * 51 + t] = a;
        }
      } else {
#pragma unroll
        for (int t = 25; t < 50; ++t) {
          float a = 0.f;
#pragma unroll
          for (int k = 31; k >= 0; --k)
            if (t - k >= 0) a += xs[t - k] * pk.k[k];
          lds[r * 51 + t] = a;
        }
      }
    }
  }
  __syncthreads();
  // ---- spike1 per s1 row (128 rows, in place) ----
  if (tid < NROW) {
    const int wol = tid & (SW - 1);
    if (group * SW + wol < S1W) {
      float buf[16];
#pragma unroll
      for (int j = 0; j < 16; ++j) buf[j] = 0.f;
#pragma unroll
      for (int t = 0; t < 50; ++t) {
        float v = lds[tid * 51 + t] + buf[t & 15];
        buf[t & 15] = 0.f;
        float sp = 0.f;
        if (v >= THETA) {
          sp = 1.f;
#pragma unroll
          for (int j = 0; j < 16; ++j) buf[(t + 1 + j) & 15] += rk.k[j];
        }
        lds[tid * 51 + t] = sp;
      }
    }
  }
  __syncthreads();
  // ---- FIR2 = pool-sum then psp2 (commuted past pool): 32 pooled rows, 2 threads/row ----
  {
    const int r = tid & 31;
    const int part = tid >> 5;                // 0..7, only part<2 active
    const int co = r >> 2;
    const int wpl = r & 3;
    const bool act = (part < 2) && (group * (SW / 2) + wpl < S2W);
    const int r00 = (co * 16 + 2 * wpl) * 51;
    const int r01 = r00 + 51;
    const int r10 = (co * 16 + 8 + 2 * wpl) * 51;
    const int r11 = r10 + 51;
    float xs[50];
    if (act) {
      if (part == 0) {
#pragma unroll
        for (int t = 0; t < 25; ++t)
          xs[t] = (((lds[r00 + t] + lds[r01 + t]) + lds[r10 + t]) + lds[r11 + t]) * 2.75f;
      } else {
#pragma unroll
        for (int t = 0; t < 50; ++t)
          xs[t] = (((lds[r00 + t] + lds[r01 + t]) + lds[r10 + t]) + lds[r11 + t]) * 2.75f;
      }
    }
    __syncthreads();
    if (act) {
      if (part == 0) {
#pragma unroll
        for (int t = 0; t < 25; ++t) {
          float a = 0.f;
#pragma unroll
          for (int k = 31; k >= 0; --k)
            if (t - k >= 0) a += xs[t - k] * pk.k[k];
          lds[r00 + t] = a;
        }
      } else {
#pragma unroll
        for (int t = 25; t < 50; ++t) {
          float a = 0.f;
#pragma unroll
          for (int k = 31; k >= 0; --k)
            if (t - k >= 0) a += xs[t - k] * pk.k[k];
          lds[r00 + t] = a;
        }
      }
    }
  }
  __syncthreads();
  // ---- spike2 -> direct store ----
  if (tid < COUT * (SW / 2)) {                // 32 threads
    const int co = tid / (SW / 2);
    const int wpl = tid % (SW / 2);
    const int wop = group * (SW / 2) + wpl;   // s2 wo
    if (wop < S2W) {
      const int rr = (co * 16 + 2 * wpl) * 51;
      float* orow = s2out + (((size_t)(n * COUT + co) * S2H + hop) * S2W + wop) * 50;
      float buf[16];
#pragma unroll
      for (int j = 0; j < 16; ++j) buf[j] = 0.f;
      float prev = 0.f;
#pragma unroll
      for (int t = 0; t < 50; ++t) {
        float v = lds[rr + t] + buf[t & 15];
        buf[t & 15] = 0.f;
        float sp = 0.f;
        if (v >= THETA) {
          sp = 1.f;
#pragma unroll
          for (int j = 0; j < 16; ++j) buf[(t + 1 + j) & 15] += rk.k[j];
        }
        if (t & 1) *(float2*)(orow + t - 1) = make_float2(prev, sp);
        else prev = sp;
      }
    }
  }
}

// ====== fused conv (stride2,pad1) + psp(commuted) + spike, direct register store ======
// Reference: spike(conv(psp(x))) == spike(psp(conv(x))) -- conv on raw binary spikes.
template <int CIN, int COUT, int KK, int WT, int HIN, int WIN, int HOUT, int WOUT>
__global__ __launch_bounds__(256)
void conv_fir_spike_kernel(const float* __restrict__ x, const float* __restrict__ w,
                           float* __restrict__ s, K32 pk, K16 rk) {
  constexpr int XR = 2 * (WT - 1) + KK;
  constexpr int TW = 4 * WT;                 // wo span per block (4 waves)
  constexpr int GROUPS = (WOUT + TW - 1) / TW;
  constexpr int NROW = COUT * TW;
  __shared__ float lds[NROW * 51];
  const int tid = threadIdx.x;
  const int wave = tid >> 6;
  const int lane = tid & 63;
  const int group = blockIdx.x % GROUPS;
  const int rest = blockIdx.x / GROUPS;
  const int ho = rest % HOUT;
  const int n = rest / HOUT;
  const int wo0 = group * TW + wave * WT;
  const int tt = lane < 50 ? lane : 49;

  float acc[COUT][WT] = {};
  for (int c = 0; c < CIN; ++c) {
#pragma unroll
    for (int kh = 0; kh < KK; ++kh) {
      const int hi = 2 * ho + kh - 1;
      if ((unsigned)hi >= (unsigned)HIN) continue;   // zero padding
      float xr[XR];
#pragma unroll
      for (int i = 0; i < XR; ++i) {
        const int wi = 2 * wo0 - 1 + i;
        xr[i] = ((unsigned)wi < (unsigned)WIN)
                    ? x[(((size_t)(n * CIN + c) * HIN + hi) * WIN + wi) * 50 + tt]
                    : 0.f;
      }
#pragma unroll
      for (int co = 0; co < COUT; ++co)
#pragma unroll
        for (int kw = 0; kw < KK; ++kw) {
          const float wv = w[((co * CIN + c) * KK + kh) * KK + kw];
#pragma unroll
          for (int wl = 0; wl < WT; ++wl)
            acc[co][wl] += xr[2 * wl + kw] * wv;
        }
    }
  }

  if (lane < 50) {
#pragma unroll
    for (int co = 0; co < COUT; ++co)
#pragma unroll
      for (int wl = 0; wl < WT; ++wl)
        lds[(co * TW + wave * WT + wl) * 51 + lane] = acc[co][wl];
  }
  __syncthreads();
  // ---- FIR = psp (commuted past conv): 2 threads/row ----
  {
    const int r = tid % NROW;
    const int part = tid / NROW;
    const int wol = r % TW;
    const bool act = (part < 2) && (group * TW + wol < WOUT);
    float xs[50];
    if (act) {
      if (part == 0) {
#pragma unroll
        for (int t = 0; t < 25; ++t) xs[t] = lds[r * 51 + t];
      } else {
#pragma unroll
        for (int t = 0; t < 50; ++t) xs[t] = lds[r * 51 + t];
      }
    }
    __syncthreads();
    if (act) {
      if (part == 0) {
#pragma unroll
        for (int t = 0; t < 25; ++t) {
          float a = 0.f;
#pragma unroll
          for (int k = 31; k >= 0; --k)
            if (t - k >= 0) a += xs[t - k] * pk.k[k];
          lds[r * 51 + t] = a;
        }
      } else {
#pragma unroll
        for (int t = 25; t < 50; ++t) {
          float a = 0.f;
#pragma unroll
          for (int k = 31; k >= 0; --k)
            if (t - k >= 0) a += xs[t - k] * pk.k[k];
          lds[r * 51 + t] = a;
        }
      }
    }
  }
  __syncthreads();
  // spike along t, one thread per output row, direct float2 store from regs
  if (tid < NROW) {
    const int co = tid / TW;
    const int wol = tid - co * TW;
    const int wo = group * TW + wol;
    if (wo < WOUT) {
      float* orow = s + (((size_t)(n * COUT + co) * HOUT + ho) * WOUT + wo) * 50;
      float buf[16];
#pragma unroll
      for (int j = 0; j < 16; ++j) buf[j] = 0.f;
      float prev = 0.f;
#pragma unroll
      for (int t = 0; t < 50; ++t) {
        float v = lds[tid * 51 + t] + buf[t & 15];
        buf[t & 15] = 0.f;
        float sp = 0.f;
        if (v >= THETA) {
          sp = 1.f;
#pragma unroll
          for (int j = 0; j < 16; ++j) buf[(t + 1 + j) & 15] += rk.k[j];
        }
        if (t & 1) *(float2*)(orow + t - 1) = make_float2(prev, sp);
        else prev = sp;
      }
    }
  }
}

// ====== pool-first + psp(commuted) + spike (layer 4) ======
// Reference: spike(pool(psp(x))) == spike(psp(pool(x))) -- pool binary spikes (exact),
// FIR on 16 pooled rows instead of 64.
__global__ __launch_bounds__(128)
void pool_fir_spike_kernel(const float* __restrict__ in, float* __restrict__ out,
                           int Hin, int Win, int Hout, int Wout, K32 pk, K16 rk) {
  __shared__ __align__(16) float lds[64 * 50 + 16 * 50];   // 16 KB
  const int tid = threadIdx.x;
  const int ho = blockIdx.x % Hout;
  const int nc = blockIdx.x / Hout;
  // two input rows are contiguous in memory: 2*Win*50 floats
  const float* b0 = in + ((size_t)(nc * Hin + 2 * ho) * Win) * 50;
  const int n4 = (2 * Win * 50) >> 2;
  const float4* g4 = (const float4*)b0;
  for (int i = tid; i < n4; i += 128) *(float4*)(&lds[4 * i]) = g4[i];
  __syncthreads();
  // ---- pool-sum snapshot + FIR: 2 threads per pooled col, write to result area ----
  {
    const int r = tid & 15;
    const int part = tid >> 4;      // 0..7, only part<2 active
    const bool act = (part < 2) && (r < Wout);
    const int c00 = (2 * r) * 50, c01 = c00 + 50;
    const int c10 = Win * 50 + c00, c11 = Win * 50 + c01;
    const int ro = 64 * 50 + r * 50;
    float xs[50];
    if (act) {
      if (part == 0) {
#pragma unroll
        for (int t = 0; t < 25; ++t)
          xs[t] = (((lds[c00 + t] + lds[c01 + t]) + lds[c10 + t]) + lds[c11 + t]) * 2.75f;
#pragma unroll
        for (int t = 0; t < 25; ++t) {
          float a = 0.f;
#pragma unroll
          for (int k = 31; k >= 0; --k)
            if (t - k >= 0) a += xs[t - k] * pk.k[k];
          lds[ro + t] = a;
        }
      } else {
#pragma unroll
        for (int t = 0; t < 50; ++t)
          xs[t] = (((lds[c00 + t] + lds[c01 + t]) + lds[c10 + t]) + lds[c11 + t]) * 2.75f;
#pragma unroll
        for (int t = 25; t < 50; ++t) {
          float a = 0.f;
#pragma unroll
          for (int k = 31; k >= 0; --k)
            if (t - k >= 0) a += xs[t - k] * pk.k[k];
          lds[ro + t] = a;
        }
      }
    }
  }
  __syncthreads();
  // ---- spike + store ----
  if (tid < 16 && tid < Wout) {
    const int ro = 64 * 50 + tid * 50;
    float* orow = out + (((size_t)nc * Hout + ho) * Wout + tid) * 50;
    float buf[16];
#pragma unroll
    for (int j = 0; j < 16; ++j) buf[j] = 0.f;
    float prev = 0.f;
#pragma unroll
    for (int t = 0; t < 50; ++t) {
      float v = lds[ro + t] + buf[t & 15];
      buf[t & 15] = 0.f;
      float sp = 0.f;
      if (v >= THETA) {
        sp = 1.f;
#pragma unroll
        for (int j = 0; j < 16; ++j) buf[(t + 1 + j) & 15] += rk.k[j];
      }
      if (t & 1) *(float2*)(orow + t - 1) = make_float2(prev, sp);
      else prev = sp;
    }
  }
}

// ====== fc + psp(commuted) + final spike ======
// Reference: spike(einsum(w, psp(s))) == spike(psp(einsum(w, s))) -- dot on binary
// spikes (exact products), FIR on the 8x50 result, then spike.
__global__ __launch_bounds__(512)
void fc_fir_spike_kernel(const float* __restrict__ w, const float* __restrict__ s,
                         float* __restrict__ out, K32 pk, K16 rk) {
  __shared__ float lds[8 * 51];
  const int tid = threadIdx.x;
  const int wave = tid >> 6, lane = tid & 63;
  const int o = wave & 1, n = wave >> 1;
  const int tt = lane < 50 ? lane : 49;
  const float* wrow = w + (size_t)o * 2048;
  const float* ub = s + (size_t)n * 2048 * 50;
  float acc = 0.f;
#pragma unroll 32
  for (int i = 0; i < 2048; ++i) acc += wrow[i] * ub[(size_t)i * 50 + tt];
  if (lane < 50) lds[wave * 51 + lane] = acc;
  __syncthreads();
  // ---- FIR = psp6 (commuted past einsum): 2 threads/row, in place ----
  {
    const int r = tid & 7;
    const int part = tid >> 3;      // only part<2 active
    const bool act = part < 2;
    float xs[50];
    if (act) {
      if (part == 0) {
#pragma unroll
        for (int t = 0; t < 25; ++t) xs[t] = lds[r * 51 + t];
      } else {
#pragma unroll
        for (int t = 0; t < 50; ++t) xs[t] = lds[r * 51 + t];
      }
    }
    __syncthreads();
    if (act) {
      if (part == 0) {
#pragma unroll
        for (int t = 0; t < 25; ++t) {
          float a = 0.f;
#pragma unroll
          for (int k = 31; k >= 0; --k)
            if (t - k >= 0) a += xs[t - k] * pk.k[k];
          lds[r * 51 + t] = a;
        }
      } else {
#pragma unroll
        for (int t = 25; t < 50; ++t) {
          float a = 0.f;
#pragma unroll
          for (int k = 31; k >= 0; --k)
            if (t - k >= 0) a += xs[t - k] * pk.k[k];
          lds[r * 51 + t] = a;
        }
      }
    }
  }
  __syncthreads();
  if (tid < 8) {
    float buf[16];
#pragma unroll
    for (int j = 0; j < 16; ++j) buf[j] = 0.f;
#pragma unroll
    for (int t = 0; t < 50; ++t) {
      float v = lds[tid * 51 + t] + buf[t & 15];
      buf[t & 15] = 0.f;
      float sp = 0.f;
      if (v >= THETA) {
        sp = 1.f;
#pragma unroll
        for (int j = 0; j < 16; ++j) buf[(t + 1 + j) & 15] += rk.k[j];
      }
      out[tid * 50 + t] = sp;
    }
  }
}

extern "C" void kernel_launch(void* const* d_in, const int* in_sizes, int n_in,
                              void* d_out, int out_size, void* d_ws, size_t ws_size,
                              hipStream_t stream) {
  const float* xin = (const float*)d_in[0];  // [4,2,256,256,50] raw binary spikes
  const float* w1  = (const float*)d_in[1];  // [8,2,5,5]
  const float* w2  = (const float*)d_in[2];  // [16,8,3,3]
  const float* w3  = (const float*)d_in[3];  // [32,16,3,3]
  const float* wfc = (const float*)d_in[4];  // [2,32,8,8]
  float* out = (float*)d_out;                // [4,2,1,1,50]

  float* R0 = (float*)d_ws;                  // 26,214,400 floats
  float* R1 = R0 + 26214400;

  K32 pk;
  for (int k = 0; k < 32; ++k)
    pk.k[k] = (float)(((double)k / 10.0) * exp(1.0 - (double)k / 10.0));
  K16 rk;
  for (int j = 0; j < 16; ++j) {
    const double tr = (double)(j + 1);
    rk.k[j] = (float)(-2.0 * 10.0 * tr * exp(1.0 - tr));
  }

  // 1. FUSED conv1+psp1+spike1+pool1+psp2+spike2: raw xin -> R0 = s2 [4,8,63,63,50]
  conv_pps_kernel<2, 8, 5, 256, 256, 127, 127, 63, 63>
      <<<4 * 63 * 16, 256, 0, stream>>>(xin, w1, R0, pk, rk);
  // 2. FUSED conv2+psp3+spike3: R0 -> R1 = s3 [4,16,32,32,50]
  conv_fir_spike_kernel<8, 16, 3, 1, 63, 63, 32, 32>
      <<<4 * 32 * 8, 256, 0, stream>>>(R0, w2, R1, pk, rk);
  // 3. FUSED pool2+psp4+spike4: R1 -> R0 = s4 [4,16,16,16,50]
  pool_fir_spike_kernel<<<4 * 16 * 16, 128, 0, stream>>>(R1, R0, 32, 32, 16, 16, pk, rk);
  // 4. FUSED conv3+psp5+spike5: R0 -> R1 = s5 [4,32,8,8,50]
  conv_fir_spike_kernel<16, 32, 3, 1, 16, 16, 8, 8>
      <<<4 * 8 * 2, 256, 0, stream>>>(R0, w3, R1, pk, rk);
  // 5. FUSED fc+psp6+final spike: R1 -> out
  fc_fir_spike_kernel<<<1, 512, 0, stream>>>(wfc, R1, out, pk, rk);
}

// Round 2
// 490.738 us; speedup vs baseline: 1.1894x; 1.1894x over previous
//
#include <hip/hip_runtime.h>
#include <cmath>

struct K32 { float k[32]; };
struct K16 { float k[16]; };

#define THETA 10.0f

// ---------------- psp v7 (proven): 64 rows / 128 threads / 12.8 KB LDS ----------------
__global__ __launch_bounds__(128)
void psp_kernel(const float* __restrict__ in, float* __restrict__ out,
                int nrows, K32 pk) {
  __shared__ __align__(16) float lds[64 * 50];
  const int rowBase = blockIdx.x * 64;
  const int tid = threadIdx.x;
  const int vr = min(64, nrows - rowBase);   // always even here
  const int n4 = (vr * 50) >> 2;
  const float4* g4 = (const float4*)(in + (size_t)rowBase * 50);
  for (int i = tid; i < n4; i += 128) *(float4*)(&lds[4 * i]) = g4[i];
  __syncthreads();
  const int r = tid & 63;
  const int part = tid >> 6;
  const bool act = r < vr;
  float x[50];
  if (act) {
    if (part == 0) {
#pragma unroll
      for (int t = 0; t < 25; ++t) x[t] = lds[r * 50 + t];
    } else {
#pragma unroll
      for (int t = 0; t < 50; ++t) x[t] = lds[r * 50 + t];
    }
  }
  __syncthreads();
  if (act) {
    if (part == 0) {
#pragma unroll
      for (int t = 0; t < 25; ++t) {
        float a = 0.f;
#pragma unroll
        for (int k = 31; k >= 0; --k)          // x-index ascending (oldest first)
          if (t - k >= 0) a += x[t - k] * pk.k[k];
        lds[r * 50 + t] = a;
      }
    } else {
#pragma unroll
      for (int t = 25; t < 50; ++t) {
        float a = 0.f;
#pragma unroll
        for (int k = 31; k >= 0; --k)
          if (t - k >= 0) a += x[t - k] * pk.k[k];
        lds[r * 50 + t] = a;
      }
    }
  }
  __syncthreads();
  float4* o4 = (float4*)(out + (size_t)rowBase * 50);
  for (int i = tid; i < n4; i += 128) o4[i] = *(const float4*)(&lds[4 * i]);
}

// ====== fused conv(stride2,pad1)+spike + psp+pool(2x2,*2.75)+spike -> s2 (R14-proven) ======
// Block: (n, s2-ho, group of 4 s2-wo) == (8co x 8 s1-wo x 2 s1-ho) = 128 LDS rows.
// Wave = (ho_off, wo_half), WT=4 -> acc[8][4]. Phases sequential:
// conv(regs) -> transpose(LDS) -> spike/row -> FIR 2thr/row -> pool+spike+store.
template <int CIN, int COUT, int KK, int HIN, int WIN, int S1H, int S1W,
          int S2H, int S2W>
__global__ __launch_bounds__(256)
void conv_pps_kernel(const float* __restrict__ x, const float* __restrict__ w,
                     float* __restrict__ s2out, K32 pk, K16 rk) {
  constexpr int WT = 4;                       // s1-wo per wave
  constexpr int SW = 8;                       // s1-wo per block
  constexpr int XR = 2 * (WT - 1) + KK;       // 11
  constexpr int GROUPS = (S1W + SW - 1) / SW; // 16
  constexpr int NROW = COUT * 2 * SW;         // 128
  __shared__ float lds[NROW * 51];            // 26 KB
  const int tid = threadIdx.x;
  const int wave = tid >> 6;
  const int lane = tid & 63;
  const int group = blockIdx.x % GROUPS;
  const int rest = blockIdx.x / GROUPS;
  const int hop = rest % S2H;                 // s2 ho
  const int n = rest / S2H;
  const int ho_off = wave & 1;
  const int wo_half = wave >> 1;
  const int ho = 2 * hop + ho_off;            // s1 ho
  const int wo0 = group * SW + wo_half * WT;
  const int tt = lane < 50 ? lane : 49;

  // ---- conv (checked loads, proven order c -> kh -> co -> kw -> wl) ----
  float acc[COUT][WT] = {};
  for (int c = 0; c < CIN; ++c) {
#pragma unroll
    for (int kh = 0; kh < KK; ++kh) {
      const int hi = 2 * ho + kh - 1;
      if ((unsigned)hi >= (unsigned)HIN) continue;   // zero padding
      float xr[XR];
#pragma unroll
      for (int i = 0; i < XR; ++i) {
        const int wi = 2 * wo0 - 1 + i;
        xr[i] = ((unsigned)wi < (unsigned)WIN)
                    ? x[(((size_t)(n * CIN + c) * HIN + hi) * WIN + wi) * 50 + tt]
                    : 0.f;
      }
#pragma unroll
      for (int co = 0; co < COUT; ++co)
#pragma unroll
        for (int kw = 0; kw < KK; ++kw) {
          const float wv = w[((co * CIN + c) * KK + kh) * KK + kw];
#pragma unroll
          for (int wl = 0; wl < WT; ++wl)
            acc[co][wl] += xr[2 * wl + kw] * wv;
        }
    }
  }
  // ---- transpose: LDS row = co*16 + ho_off*8 + wol ----
  if (lane < 50) {
#pragma unroll
    for (int co = 0; co < COUT; ++co)
#pragma unroll
      for (int wl = 0; wl < WT; ++wl)
        lds[((co * 2 + ho_off) * SW + wo_half * WT + wl) * 51 + lane] = acc[co][wl];
  }
  __syncthreads();
  // ---- spike per s1 row (128 rows, in place) ----
  if (tid < NROW) {
    const int wol = tid & (SW - 1);
    if (group * SW + wol < S1W) {
      float buf[16];
#pragma unroll
      for (int j = 0; j < 16; ++j) buf[j] = 0.f;
#pragma unroll
      for (int t = 0; t < 50; ++t) {
        float v = lds[tid * 51 + t] + buf[t & 15];
        buf[t & 15] = 0.f;
        float sp = 0.f;
        if (v >= THETA) {
          sp = 1.f;
#pragma unroll
          for (int j = 0; j < 16; ++j) buf[(t + 1 + j) & 15] += rk.k[j];
        }
        lds[tid * 51 + t] = sp;
      }
    }
  }
  __syncthreads();
  // ---- FIR (psp2) per s1 row: 2 threads/row, snapshot -> barrier -> in-place ----
  {
    const int r = tid & (NROW - 1);
    const int part = tid >> 7;
    const int wol = r & (SW - 1);
    const bool act = (group * SW + wol) < S1W;
    float xs[50];
    if (act) {
      if (part == 0) {
#pragma unroll
        for (int t = 0; t < 25; ++t) xs[t] = lds[r * 51 + t];
      } else {
#pragma unroll
        for (int t = 0; t < 50; ++t) xs[t] = lds[r * 51 + t];
      }
    }
    __syncthreads();
    if (act) {
      if (part == 0) {
#pragma unroll
        for (int t = 0; t < 25; ++t) {
          float a = 0.f;
#pragma unroll
          for (int k = 31; k >= 0; --k)
            if (t - k >= 0) a += xs[t - k] * pk.k[k];
          lds[r * 51 + t] = a;
        }
      } else {
#pragma unroll
        for (int t = 25; t < 50; ++t) {
          float a = 0.f;
#pragma unroll
          for (int k = 31; k >= 0; --k)
            if (t - k >= 0) a += xs[t - k] * pk.k[k];
          lds[r * 51 + t] = a;
        }
      }
    }
  }
  __syncthreads();
  // ---- pool ((h0w0+h0w1)+h1w0)+h1w1 * 2.75 -> spike -> direct store ----
  if (tid < COUT * (SW / 2)) {                // 32 threads
    const int co = tid / (SW / 2);
    const int wpl = tid % (SW / 2);
    const int wop = group * (SW / 2) + wpl;   // s2 wo
    if (wop < S2W) {
      const int r00 = (co * 16 + 2 * wpl) * 51;
      const int r01 = (co * 16 + 2 * wpl + 1) * 51;
      const int r10 = (co * 16 + 8 + 2 * wpl) * 51;
      const int r11 = (co * 16 + 8 + 2 * wpl + 1) * 51;
      float* orow = s2out + (((size_t)(n * COUT + co) * S2H + hop) * S2W + wop) * 50;
      float buf[16];
#pragma unroll
      for (int j = 0; j < 16; ++j) buf[j] = 0.f;
      float prev = 0.f;
#pragma unroll
      for (int t = 0; t < 50; ++t) {
        const float u0 = (((lds[r00 + t] + lds[r01 + t]) + lds[r10 + t]) + lds[r11 + t]) * 2.75f;
        float v = u0 + buf[t & 15];
        buf[t & 15] = 0.f;
        float sp = 0.f;
        if (v >= THETA) {
          sp = 1.f;
#pragma unroll
          for (int j = 0; j < 16; ++j) buf[(t + 1 + j) & 15] += rk.k[j];
        }
        if (t & 1) *(float2*)(orow + t - 1) = make_float2(prev, sp);
        else prev = sp;
      }
    }
  }
}

// ====== fused conv (stride2,pad1) + psp(commuted) + spike (verified R1) ======
// Reference: spike(conv(psp(x))) == spike(psp(conv(x))) -- conv on raw binary spikes.
template <int CIN, int COUT, int KK, int WT, int HIN, int WIN, int HOUT, int WOUT>
__global__ __launch_bounds__(256)
void conv_fir_spike_kernel(const float* __restrict__ x, const float* __restrict__ w,
                           float* __restrict__ s, K32 pk, K16 rk) {
  constexpr int XR = 2 * (WT - 1) + KK;
  constexpr int TW = 4 * WT;                 // wo span per block (4 waves)
  constexpr int GROUPS = (WOUT + TW - 1) / TW;
  constexpr int NROW = COUT * TW;
  __shared__ float lds[NROW * 51];
  const int tid = threadIdx.x;
  const int wave = tid >> 6;
  const int lane = tid & 63;
  const int group = blockIdx.x % GROUPS;
  const int rest = blockIdx.x / GROUPS;
  const int ho = rest % HOUT;
  const int n = rest / HOUT;
  const int wo0 = group * TW + wave * WT;
  const int tt = lane < 50 ? lane : 49;

  float acc[COUT][WT] = {};
  for (int c = 0; c < CIN; ++c) {
#pragma unroll
    for (int kh = 0; kh < KK; ++kh) {
      const int hi = 2 * ho + kh - 1;
      if ((unsigned)hi >= (unsigned)HIN) continue;   // zero padding
      float xr[XR];
#pragma unroll
      for (int i = 0; i < XR; ++i) {
        const int wi = 2 * wo0 - 1 + i;
        xr[i] = ((unsigned)wi < (unsigned)WIN)
                    ? x[(((size_t)(n * CIN + c) * HIN + hi) * WIN + wi) * 50 + tt]
                    : 0.f;
      }
#pragma unroll
      for (int co = 0; co < COUT; ++co)
#pragma unroll
        for (int kw = 0; kw < KK; ++kw) {
          const float wv = w[((co * CIN + c) * KK + kh) * KK + kw];
#pragma unroll
          for (int wl = 0; wl < WT; ++wl)
            acc[co][wl] += xr[2 * wl + kw] * wv;
        }
    }
  }

  if (lane < 50) {
#pragma unroll
    for (int co = 0; co < COUT; ++co)
#pragma unroll
      for (int wl = 0; wl < WT; ++wl)
        lds[(co * TW + wave * WT + wl) * 51 + lane] = acc[co][wl];
  }
  __syncthreads();
  // ---- FIR = psp (commuted past conv): 2 threads/row ----
  {
    const int r = tid % NROW;
    const int part = tid / NROW;
    const int wol = r % TW;
    const bool act = (part < 2) && (group * TW + wol < WOUT);
    float xs[50];
    if (act) {
      if (part == 0) {
#pragma unroll
        for (int t = 0; t < 25; ++t) xs[t] = lds[r * 51 + t];
      } else {
#pragma unroll
        for (int t = 0; t < 50; ++t) xs[t] = lds[r * 51 + t];
      }
    }
    __syncthreads();
    if (act) {
      if (part == 0) {
#pragma unroll
        for (int t = 0; t < 25; ++t) {
          float a = 0.f;
#pragma unroll
          for (int k = 31; k >= 0; --k)
            if (t - k >= 0) a += xs[t - k] * pk.k[k];
          lds[r * 51 + t] = a;
        }
      } else {
#pragma unroll
        for (int t = 25; t < 50; ++t) {
          float a = 0.f;
#pragma unroll
          for (int k = 31; k >= 0; --k)
            if (t - k >= 0) a += xs[t - k] * pk.k[k];
          lds[r * 51 + t] = a;
        }
      }
    }
  }
  __syncthreads();
  // spike along t, one thread per output row, direct float2 store from regs
  if (tid < NROW) {
    const int co = tid / TW;
    const int wol = tid - co * TW;
    const int wo = group * TW + wol;
    if (wo < WOUT) {
      float* orow = s + (((size_t)(n * COUT + co) * HOUT + ho) * WOUT + wo) * 50;
      float buf[16];
#pragma unroll
      for (int j = 0; j < 16; ++j) buf[j] = 0.f;
      float prev = 0.f;
#pragma unroll
      for (int t = 0; t < 50; ++t) {
        float v = lds[tid * 51 + t] + buf[t & 15];
        buf[t & 15] = 0.f;
        float sp = 0.f;
        if (v >= THETA) {
          sp = 1.f;
#pragma unroll
          for (int j = 0; j < 16; ++j) buf[(t + 1 + j) & 15] += rk.k[j];
        }
        if (t & 1) *(float2*)(orow + t - 1) = make_float2(prev, sp);
        else prev = sp;
      }
    }
  }
}

// ====== pool-first + psp(commuted) + spike (layer 4, verified R1) ======
__global__ __launch_bounds__(128)
void pool_fir_spike_kernel(const float* __restrict__ in, float* __restrict__ out,
                           int Hin, int Win, int Hout, int Wout, K32 pk, K16 rk) {
  __shared__ __align__(16) float lds[64 * 50 + 16 * 50];   // 16 KB
  const int tid = threadIdx.x;
  const int ho = blockIdx.x % Hout;
  const int nc = blockIdx.x / Hout;
  // two input rows are contiguous in memory: 2*Win*50 floats
  const float* b0 = in + ((size_t)(nc * Hin + 2 * ho) * Win) * 50;
  const int n4 = (2 * Win * 50) >> 2;
  const float4* g4 = (const float4*)b0;
  for (int i = tid; i < n4; i += 128) *(float4*)(&lds[4 * i]) = g4[i];
  __syncthreads();
  // ---- pool-sum snapshot + FIR: 2 threads per pooled col, write to result area ----
  {
    const int r = tid & 15;
    const int part = tid >> 4;      // 0..7, only part<2 active
    const bool act = (part < 2) && (r < Wout);
    const int c00 = (2 * r) * 50, c01 = c00 + 50;
    const int c10 = Win * 50 + c00, c11 = Win * 50 + c01;
    const int ro = 64 * 50 + r * 50;
    float xs[50];
    if (act) {
      if (part == 0) {
#pragma unroll
        for (int t = 0; t < 25; ++t)
          xs[t] = (((lds[c00 + t] + lds[c01 + t]) + lds[c10 + t]) + lds[c11 + t]) * 2.75f;
#pragma unroll
        for (int t = 0; t < 25; ++t) {
          float a = 0.f;
#pragma unroll
          for (int k = 31; k >= 0; --k)
            if (t - k >= 0) a += xs[t - k] * pk.k[k];
          lds[ro + t] = a;
        }
      } else {
#pragma unroll
        for (int t = 0; t < 50; ++t)
          xs[t] = (((lds[c00 + t] + lds[c01 + t]) + lds[c10 + t]) + lds[c11 + t]) * 2.75f;
#pragma unroll
        for (int t = 25; t < 50; ++t) {
          float a = 0.f;
#pragma unroll
          for (int k = 31; k >= 0; --k)
            if (t - k >= 0) a += xs[t - k] * pk.k[k];
          lds[ro + t] = a;
        }
      }
    }
  }
  __syncthreads();
  // ---- spike + store ----
  if (tid < 16 && tid < Wout) {
    const int ro = 64 * 50 + tid * 50;
    float* orow = out + (((size_t)nc * Hout + ho) * Wout + tid) * 50;
    float buf[16];
#pragma unroll
    for (int j = 0; j < 16; ++j) buf[j] = 0.f;
    float prev = 0.f;
#pragma unroll
    for (int t = 0; t < 50; ++t) {
      float v = lds[ro + t] + buf[t & 15];
      buf[t & 15] = 0.f;
      float sp = 0.f;
      if (v >= THETA) {
        sp = 1.f;
#pragma unroll
        for (int j = 0; j < 16; ++j) buf[(t + 1 + j) & 15] += rk.k[j];
      }
      if (t & 1) *(float2*)(orow + t - 1) = make_float2(prev, sp);
      else prev = sp;
    }
  }
}

// ====== fc + psp(commuted) + final spike (verified R1) ======
__global__ __launch_bounds__(512)
void fc_fir_spike_kernel(const float* __restrict__ w, const float* __restrict__ s,
                         float* __restrict__ out, K32 pk, K16 rk) {
  __shared__ float lds[8 * 51];
  const int tid = threadIdx.x;
  const int wave = tid >> 6, lane = tid & 63;
  const int o = wave & 1, n = wave >> 1;
  const int tt = lane < 50 ? lane : 49;
  const float* wrow = w + (size_t)o * 2048;
  const float* ub = s + (size_t)n * 2048 * 50;
  float acc = 0.f;
#pragma unroll 32
  for (int i = 0; i < 2048; ++i) acc += wrow[i] * ub[(size_t)i * 50 + tt];
  if (lane < 50) lds[wave * 51 + lane] = acc;
  __syncthreads();
  // ---- FIR = psp6 (commuted past einsum): 2 threads/row, in place ----
  {
    const int r = tid & 7;
    const int part = tid >> 3;      // only part<2 active
    const bool act = part < 2;
    float xs[50];
    if (act) {
      if (part == 0) {
#pragma unroll
        for (int t = 0; t < 25; ++t) xs[t] = lds[r * 51 + t];
      } else {
#pragma unroll
        for (int t = 0; t < 50; ++t) xs[t] = lds[r * 51 + t];
      }
    }
    __syncthreads();
    if (act) {
      if (part == 0) {
#pragma unroll
        for (int t = 0; t < 25; ++t) {
          float a = 0.f;
#pragma unroll
          for (int k = 31; k >= 0; --k)
            if (t - k >= 0) a += xs[t - k] * pk.k[k];
          lds[r * 51 + t] = a;
        }
      } else {
#pragma unroll
        for (int t = 25; t < 50; ++t) {
          float a = 0.f;
#pragma unroll
          for (int k = 31; k >= 0; --k)
            if (t - k >= 0) a += xs[t - k] * pk.k[k];
          lds[r * 51 + t] = a;
        }
      }
    }
  }
  __syncthreads();
  if (tid < 8) {
    float buf[16];
#pragma unroll
    for (int j = 0; j < 16; ++j) buf[j] = 0.f;
#pragma unroll
    for (int t = 0; t < 50; ++t) {
      float v = lds[tid * 51 + t] + buf[t & 15];
      buf[t & 15] = 0.f;
      float sp = 0.f;
      if (v >= THETA) {
        sp = 1.f;
#pragma unroll
        for (int j = 0; j < 16; ++j) buf[(t + 1 + j) & 15] += rk.k[j];
      }
      out[tid * 50 + t] = sp;
    }
  }
}

extern "C" void kernel_launch(void* const* d_in, const int* in_sizes, int n_in,
                              void* d_out, int out_size, void* d_ws, size_t ws_size,
                              hipStream_t stream) {
  const float* xin = (const float*)d_in[0];  // [4,2,256,256,50]
  const float* w1  = (const float*)d_in[1];  // [8,2,5,5]
  const float* w2  = (const float*)d_in[2];  // [16,8,3,3]
  const float* w3  = (const float*)d_in[3];  // [32,16,3,3]
  const float* wfc = (const float*)d_in[4];  // [2,32,8,8]
  float* out = (float*)d_out;                // [4,2,1,1,50]

  float* R0 = (float*)d_ws;                  // 26,214,400 floats
  float* R1 = R0 + 26214400;

  K32 pk;
  for (int k = 0; k < 32; ++k)
    pk.k[k] = (float)(((double)k / 10.0) * exp(1.0 - (double)k / 10.0));
  K16 rk;
  for (int j = 0; j < 16; ++j) {
    const double tr = (double)(j + 1);
    rk.k[j] = (float)(-2.0 * 10.0 * tr * exp(1.0 - tr));
  }

  // 1. psp1: xin -> R0 = u1 (524288 rows)  [proven R13 kernel]
  psp_kernel<<<8192, 128, 0, stream>>>(xin, R0, 524288, pk);
  // 2. FUSED conv1+spike1+psp2+pool1+spike2: R0 -> R1 = s2 [4,8,63,63,50]  [proven R14 kernel]
  conv_pps_kernel<2, 8, 5, 256, 256, 127, 127, 63, 63>
      <<<4 * 63 * 16, 256, 0, stream>>>(R0, w1, R1, pk, rk);
  // 3. FUSED conv2+psp3+spike3: R1 -> R0 = s3 [4,16,32,32,50]  (no standalone psp3)
  conv_fir_spike_kernel<8, 16, 3, 1, 63, 63, 32, 32>
      <<<4 * 32 * 8, 256, 0, stream>>>(R1, w2, R0, pk, rk);
  // 4. FUSED pool2+psp4+spike4: R0 -> R1 = s4 [4,16,16,16,50]
  pool_fir_spike_kernel<<<4 * 16 * 16, 128, 0, stream>>>(R0, R1, 32, 32, 16, 16, pk, rk);
  // 5. FUSED conv3+psp5+spike5: R1 -> R0 = s5 [4,32,8,8,50]  (no standalone psp5)
  conv_fir_spike_kernel<16, 32, 3, 1, 16, 16, 8, 8>
      <<<4 * 8 * 2, 256, 0, stream>>>(R1, w3, R0, pk, rk);
  // 6. FUSED fc+psp6+final spike: R0 -> out  (no standalone psp6)
  fc_fir_spike_kernel<<<1, 512, 0, stream>>>(wfc, R0, out, pk, rk);
}

// Round 3
// 482.743 us; speedup vs baseline: 1.2091x; 1.0166x over previous
//
#include <hip/hip_runtime.h>
#include <cmath>

struct K32 { float k[32]; };
struct K16 { float k[16]; };

#define THETA 10.0f

// ---------------- psp v8: 64 rows / 128 threads, balanced split at t=32 ----------------
__global__ __launch_bounds__(128)
void psp_kernel(const float* __restrict__ in, float* __restrict__ out,
                int nrows, K32 pk) {
  __shared__ __align__(16) float lds[64 * 50];
  const int rowBase = blockIdx.x * 64;
  const int tid = threadIdx.x;
  const int vr = min(64, nrows - rowBase);   // always even here
  const int n4 = (vr * 50) >> 2;
  const float4* g4 = (const float4*)(in + (size_t)rowBase * 50);
  for (int i = tid; i < n4; i += 128) *(float4*)(&lds[4 * i]) = g4[i];
  __syncthreads();
  const int r = tid & 63;
  const int part = tid >> 6;
  const bool act = r < vr;
  float x[50];
  if (act) {
    if (part == 0) {
#pragma unroll
      for (int t = 0; t < 32; ++t) x[t] = lds[r * 50 + t];
    } else {
#pragma unroll
      for (int t = 0; t < 50; ++t) x[t] = lds[r * 50 + t];
    }
  }
  __syncthreads();
  if (act) {
    if (part == 0) {
#pragma unroll
      for (int t = 0; t < 32; ++t) {
        float a = 0.f;
#pragma unroll
        for (int k = 31; k >= 0; --k)          // x-index ascending (oldest first)
          if (t - k >= 0) a += x[t - k] * pk.k[k];
        lds[r * 50 + t] = a;
      }
    } else {
#pragma unroll
      for (int t = 32; t < 50; ++t) {
        float a = 0.f;
#pragma unroll
        for (int k = 31; k >= 0; --k)
          a += x[t - k] * pk.k[k];             // t-k >= 1 always valid
        lds[r * 50 + t] = a;
      }
    }
  }
  __syncthreads();
  float4* o4 = (float4*)(out + (size_t)rowBase * 50);
  for (int i = tid; i < n4; i += 128) o4[i] = *(const float4*)(&lds[4 * i]);
}

// ====== fused conv(stride2,pad1)+spike + psp+pool(2x2,*2.75)+spike -> s2 ======
// R3: spike1+FIR fused into one register-resident phase (2 thr/row, spike
// recomputed per part), FIR split balanced at t=32. Removes spike LDS
// writeback + FIR snapshot round-trip + 1 barrier.
template <int CIN, int COUT, int KK, int HIN, int WIN, int S1H, int S1W,
          int S2H, int S2W>
__global__ __launch_bounds__(256)
void conv_pps_kernel(const float* __restrict__ x, const float* __restrict__ w,
                     float* __restrict__ s2out, K32 pk, K16 rk) {
  constexpr int WT = 4;                       // s1-wo per wave
  constexpr int SW = 8;                       // s1-wo per block
  constexpr int XR = 2 * (WT - 1) + KK;       // 11
  constexpr int GROUPS = (S1W + SW - 1) / SW; // 16
  constexpr int NROW = COUT * 2 * SW;         // 128
  __shared__ float lds[NROW * 51];            // 26 KB
  const int tid = threadIdx.x;
  const int wave = tid >> 6;
  const int lane = tid & 63;
  const int group = blockIdx.x % GROUPS;
  const int rest = blockIdx.x / GROUPS;
  const int hop = rest % S2H;                 // s2 ho
  const int n = rest / S2H;
  const int ho_off = wave & 1;
  const int wo_half = wave >> 1;
  const int ho = 2 * hop + ho_off;            // s1 ho
  const int wo0 = group * SW + wo_half * WT;
  const int tt = lane < 50 ? lane : 49;

  // ---- conv (checked loads, proven order c -> kh -> co -> kw -> wl) ----
  float acc[COUT][WT] = {};
  for (int c = 0; c < CIN; ++c) {
#pragma unroll
    for (int kh = 0; kh < KK; ++kh) {
      const int hi = 2 * ho + kh - 1;
      if ((unsigned)hi >= (unsigned)HIN) continue;   // zero padding
      float xr[XR];
#pragma unroll
      for (int i = 0; i < XR; ++i) {
        const int wi = 2 * wo0 - 1 + i;
        xr[i] = ((unsigned)wi < (unsigned)WIN)
                    ? x[(((size_t)(n * CIN + c) * HIN + hi) * WIN + wi) * 50 + tt]
                    : 0.f;
      }
#pragma unroll
      for (int co = 0; co < COUT; ++co)
#pragma unroll
        for (int kw = 0; kw < KK; ++kw) {
          const float wv = w[((co * CIN + c) * KK + kh) * KK + kw];
#pragma unroll
          for (int wl = 0; wl < WT; ++wl)
            acc[co][wl] += xr[2 * wl + kw] * wv;
        }
    }
  }
  // ---- transpose: LDS row = co*16 + ho_off*8 + wol ----
  if (lane < 50) {
#pragma unroll
    for (int co = 0; co < COUT; ++co)
#pragma unroll
      for (int wl = 0; wl < WT; ++wl)
        lds[((co * 2 + ho_off) * SW + wo_half * WT + wl) * 51 + lane] = acc[co][wl];
  }
  __syncthreads();
  // ---- FUSED spike1 + FIR(psp2): 2 threads/row; each part batch-reads its
  //      conv-u span into regs, recomputes spikes in regs (bit-identical on
  //      both parts), then writes only its FIR half back to LDS. ----
  {
    const int r = tid & (NROW - 1);
    const int part = tid >> 7;                // 0: y[0..31], 1: y[32..49]
    const int wol = r & (SW - 1);
    const bool act = (group * SW + wol) < S1W;
    float xs[50];
    if (act) {
      if (part == 0) {
#pragma unroll
        for (int t = 0; t < 32; ++t) xs[t] = lds[r * 51 + t];
      } else {
#pragma unroll
        for (int t = 0; t < 50; ++t) xs[t] = lds[r * 51 + t];
      }
    }
    __syncthreads();                          // all reads done before any FIR write
    if (act) {
      if (part == 0) {
        float buf[16];
#pragma unroll
        for (int j = 0; j < 16; ++j) buf[j] = 0.f;
#pragma unroll
        for (int t = 0; t < 32; ++t) {        // spike in regs (t 0..31 suffices)
          float v = xs[t] + buf[t & 15];
          buf[t & 15] = 0.f;
          float sp = 0.f;
          if (v >= THETA) {
            sp = 1.f;
#pragma unroll
            for (int j = 0; j < 16; ++j) buf[(t + 1 + j) & 15] += rk.k[j];
          }
          xs[t] = sp;
        }
#pragma unroll
        for (int t = 0; t < 32; ++t) {        // FIR y[0..31]
          float a = 0.f;
#pragma unroll
          for (int k = 31; k >= 0; --k)
            if (t - k >= 0) a += xs[t - k] * pk.k[k];
          lds[r * 51 + t] = a;
        }
      } else {
        float buf[16];
#pragma unroll
        for (int j = 0; j < 16; ++j) buf[j] = 0.f;
#pragma unroll
        for (int t = 0; t < 50; ++t) {        // spike in regs (full row)
          float v = xs[t] + buf[t & 15];
          buf[t & 15] = 0.f;
          float sp = 0.f;
          if (v >= THETA) {
            sp = 1.f;
#pragma unroll
            for (int j = 0; j < 16; ++j) buf[(t + 1 + j) & 15] += rk.k[j];
          }
          xs[t] = sp;
        }
#pragma unroll
        for (int t = 32; t < 50; ++t) {       // FIR y[32..49], all 32 taps valid
          float a = 0.f;
#pragma unroll
          for (int k = 31; k >= 0; --k)
            a += xs[t - k] * pk.k[k];
          lds[r * 51 + t] = a;
        }
      }
    }
  }
  __syncthreads();
  // ---- pool ((h0w0+h0w1)+h1w0)+h1w1 * 2.75 -> spike -> direct store ----
  if (tid < COUT * (SW / 2)) {                // 32 threads
    const int co = tid / (SW / 2);
    const int wpl = tid % (SW / 2);
    const int wop = group * (SW / 2) + wpl;   // s2 wo
    if (wop < S2W) {
      const int r00 = (co * 16 + 2 * wpl) * 51;
      const int r01 = (co * 16 + 2 * wpl + 1) * 51;
      const int r10 = (co * 16 + 8 + 2 * wpl) * 51;
      const int r11 = (co * 16 + 8 + 2 * wpl + 1) * 51;
      float* orow = s2out + (((size_t)(n * COUT + co) * S2H + hop) * S2W + wop) * 50;
      float buf[16];
#pragma unroll
      for (int j = 0; j < 16; ++j) buf[j] = 0.f;
      float prev = 0.f;
#pragma unroll
      for (int t = 0; t < 50; ++t) {
        const float u0 = (((lds[r00 + t] + lds[r01 + t]) + lds[r10 + t]) + lds[r11 + t]) * 2.75f;
        float v = u0 + buf[t & 15];
        buf[t & 15] = 0.f;
        float sp = 0.f;
        if (v >= THETA) {
          sp = 1.f;
#pragma unroll
          for (int j = 0; j < 16; ++j) buf[(t + 1 + j) & 15] += rk.k[j];
        }
        if (t & 1) *(float2*)(orow + t - 1) = make_float2(prev, sp);
        else prev = sp;
      }
    }
  }
}

// ====== fused conv (stride2,pad1) + psp(commuted) + spike (verified R1/R2) ======
// Reference: spike(conv(psp(x))) == spike(psp(conv(x))) -- conv on raw binary spikes.
template <int CIN, int COUT, int KK, int WT, int HIN, int WIN, int HOUT, int WOUT>
__global__ __launch_bounds__(256)
void conv_fir_spike_kernel(const float* __restrict__ x, const float* __restrict__ w,
                           float* __restrict__ s, K32 pk, K16 rk) {
  constexpr int XR = 2 * (WT - 1) + KK;
  constexpr int TW = 4 * WT;                 // wo span per block (4 waves)
  constexpr int GROUPS = (WOUT + TW - 1) / TW;
  constexpr int NROW = COUT * TW;
  __shared__ float lds[NROW * 51];
  const int tid = threadIdx.x;
  const int wave = tid >> 6;
  const int lane = tid & 63;
  const int group = blockIdx.x % GROUPS;
  const int rest = blockIdx.x / GROUPS;
  const int ho = rest % HOUT;
  const int n = rest / HOUT;
  const int wo0 = group * TW + wave * WT;
  const int tt = lane < 50 ? lane : 49;

  float acc[COUT][WT] = {};
  for (int c = 0; c < CIN; ++c) {
#pragma unroll
    for (int kh = 0; kh < KK; ++kh) {
      const int hi = 2 * ho + kh - 1;
      if ((unsigned)hi >= (unsigned)HIN) continue;   // zero padding
      float xr[XR];
#pragma unroll
      for (int i = 0; i < XR; ++i) {
        const int wi = 2 * wo0 - 1 + i;
        xr[i] = ((unsigned)wi < (unsigned)WIN)
                    ? x[(((size_t)(n * CIN + c) * HIN + hi) * WIN + wi) * 50 + tt]
                    : 0.f;
      }
#pragma unroll
      for (int co = 0; co < COUT; ++co)
#pragma unroll
        for (int kw = 0; kw < KK; ++kw) {
          const float wv = w[((co * CIN + c) * KK + kh) * KK + kw];
#pragma unroll
          for (int wl = 0; wl < WT; ++wl)
            acc[co][wl] += xr[2 * wl + kw] * wv;
        }
    }
  }

  if (lane < 50) {
#pragma unroll
    for (int co = 0; co < COUT; ++co)
#pragma unroll
      for (int wl = 0; wl < WT; ++wl)
        lds[(co * TW + wave * WT + wl) * 51 + lane] = acc[co][wl];
  }
  __syncthreads();
  // ---- FIR = psp (commuted past conv): 2 threads/row ----
  {
    const int r = tid % NROW;
    const int part = tid / NROW;
    const int wol = r % TW;
    const bool act = (part < 2) && (group * TW + wol < WOUT);
    float xs[50];
    if (act) {
      if (part == 0) {
#pragma unroll
        for (int t = 0; t < 25; ++t) xs[t] = lds[r * 51 + t];
      } else {
#pragma unroll
        for (int t = 0; t < 50; ++t) xs[t] = lds[r * 51 + t];
      }
    }
    __syncthreads();
    if (act) {
      if (part == 0) {
#pragma unroll
        for (int t = 0; t < 25; ++t) {
          float a = 0.f;
#pragma unroll
          for (int k = 31; k >= 0; --k)
            if (t - k >= 0) a += xs[t - k] * pk.k[k];
          lds[r * 51 + t] = a;
        }
      } else {
#pragma unroll
        for (int t = 25; t < 50; ++t) {
          float a = 0.f;
#pragma unroll
          for (int k = 31; k >= 0; --k)
            if (t - k >= 0) a += xs[t - k] * pk.k[k];
          lds[r * 51 + t] = a;
        }
      }
    }
  }
  __syncthreads();
  // spike along t, one thread per output row, direct float2 store from regs
  if (tid < NROW) {
    const int co = tid / TW;
    const int wol = tid - co * TW;
    const int wo = group * TW + wol;
    if (wo < WOUT) {
      float* orow = s + (((size_t)(n * COUT + co) * HOUT + ho) * WOUT + wo) * 50;
      float buf[16];
#pragma unroll
      for (int j = 0; j < 16; ++j) buf[j] = 0.f;
      float prev = 0.f;
#pragma unroll
      for (int t = 0; t < 50; ++t) {
        float v = lds[tid * 51 + t] + buf[t & 15];
        buf[t & 15] = 0.f;
        float sp = 0.f;
        if (v >= THETA) {
          sp = 1.f;
#pragma unroll
          for (int j = 0; j < 16; ++j) buf[(t + 1 + j) & 15] += rk.k[j];
        }
        if (t & 1) *(float2*)(orow + t - 1) = make_float2(prev, sp);
        else prev = sp;
      }
    }
  }
}

// ====== pool-first + psp(commuted) + spike (layer 4, verified R1/R2) ======
__global__ __launch_bounds__(128)
void pool_fir_spike_kernel(const float* __restrict__ in, float* __restrict__ out,
                           int Hin, int Win, int Hout, int Wout, K32 pk, K16 rk) {
  __shared__ __align__(16) float lds[64 * 50 + 16 * 50];   // 16 KB
  const int tid = threadIdx.x;
  const int ho = blockIdx.x % Hout;
  const int nc = blockIdx.x / Hout;
  // two input rows are contiguous in memory: 2*Win*50 floats
  const float* b0 = in + ((size_t)(nc * Hin + 2 * ho) * Win) * 50;
  const int n4 = (2 * Win * 50) >> 2;
  const float4* g4 = (const float4*)b0;
  for (int i = tid; i < n4; i += 128) *(float4*)(&lds[4 * i]) = g4[i];
  __syncthreads();
  // ---- pool-sum snapshot + FIR: 2 threads per pooled col, write to result area ----
  {
    const int r = tid & 15;
    const int part = tid >> 4;      // 0..7, only part<2 active
    const bool act = (part < 2) && (r < Wout);
    const int c00 = (2 * r) * 50, c01 = c00 + 50;
    const int c10 = Win * 50 + c00, c11 = Win * 50 + c01;
    const int ro = 64 * 50 + r * 50;
    float xs[50];
    if (act) {
      if (part == 0) {
#pragma unroll
        for (int t = 0; t < 25; ++t)
          xs[t] = (((lds[c00 + t] + lds[c01 + t]) + lds[c10 + t]) + lds[c11 + t]) * 2.75f;
#pragma unroll
        for (int t = 0; t < 25; ++t) {
          float a = 0.f;
#pragma unroll
          for (int k = 31; k >= 0; --k)
            if (t - k >= 0) a += xs[t - k] * pk.k[k];
          lds[ro + t] = a;
        }
      } else {
#pragma unroll
        for (int t = 0; t < 50; ++t)
          xs[t] = (((lds[c00 + t] + lds[c01 + t]) + lds[c10 + t]) + lds[c11 + t]) * 2.75f;
#pragma unroll
        for (int t = 25; t < 50; ++t) {
          float a = 0.f;
#pragma unroll
          for (int k = 31; k >= 0; --k)
            if (t - k >= 0) a += xs[t - k] * pk.k[k];
          lds[ro + t] = a;
        }
      }
    }
  }
  __syncthreads();
  // ---- spike + store ----
  if (tid < 16 && tid < Wout) {
    const int ro = 64 * 50 + tid * 50;
    float* orow = out + (((size_t)nc * Hout + ho) * Wout + tid) * 50;
    float buf[16];
#pragma unroll
    for (int j = 0; j < 16; ++j) buf[j] = 0.f;
    float prev = 0.f;
#pragma unroll
    for (int t = 0; t < 50; ++t) {
      float v = lds[ro + t] + buf[t & 15];
      buf[t & 15] = 0.f;
      float sp = 0.f;
      if (v >= THETA) {
        sp = 1.f;
#pragma unroll
        for (int j = 0; j < 16; ++j) buf[(t + 1 + j) & 15] += rk.k[j];
      }
      if (t & 1) *(float2*)(orow + t - 1) = make_float2(prev, sp);
      else prev = sp;
    }
  }
}

// ====== fc + psp(commuted) + final spike (verified R1/R2) ======
__global__ __launch_bounds__(512)
void fc_fir_spike_kernel(const float* __restrict__ w, const float* __restrict__ s,
                         float* __restrict__ out, K32 pk, K16 rk) {
  __shared__ float lds[8 * 51];
  const int tid = threadIdx.x;
  const int wave = tid >> 6, lane = tid & 63;
  const int o = wave & 1, n = wave >> 1;
  const int tt = lane < 50 ? lane : 49;
  const float* wrow = w + (size_t)o * 2048;
  const float* ub = s + (size_t)n * 2048 * 50;
  float acc = 0.f;
#pragma unroll 32
  for (int i = 0; i < 2048; ++i) acc += wrow[i] * ub[(size_t)i * 50 + tt];
  if (lane < 50) lds[wave * 51 + lane] = acc;
  __syncthreads();
  // ---- FIR = psp6 (commuted past einsum): 2 threads/row, in place ----
  {
    const int r = tid & 7;
    const int part = tid >> 3;      // only part<2 active
    const bool act = part < 2;
    float xs[50];
    if (act) {
      if (part == 0) {
#pragma unroll
        for (int t = 0; t < 25; ++t) xs[t] = lds[r * 51 + t];
      } else {
#pragma unroll
        for (int t = 0; t < 50; ++t) xs[t] = lds[r * 51 + t];
      }
    }
    __syncthreads();
    if (act) {
      if (part == 0) {
#pragma unroll
        for (int t = 0; t < 25; ++t) {
          float a = 0.f;
#pragma unroll
          for (int k = 31; k >= 0; --k)
            if (t - k >= 0) a += xs[t - k] * pk.k[k];
          lds[r * 51 + t] = a;
        }
      } else {
#pragma unroll
        for (int t = 25; t < 50; ++t) {
          float a = 0.f;
#pragma unroll
          for (int k = 31; k >= 0; --k)
            if (t - k >= 0) a += xs[t - k] * pk.k[k];
          lds[r * 51 + t] = a;
        }
      }
    }
  }
  __syncthreads();
  if (tid < 8) {
    float buf[16];
#pragma unroll
    for (int j = 0; j < 16; ++j) buf[j] = 0.f;
#pragma unroll
    for (int t = 0; t < 50; ++t) {
      float v = lds[tid * 51 + t] + buf[t & 15];
      buf[t & 15] = 0.f;
      float sp = 0.f;
      if (v >= THETA) {
        sp = 1.f;
#pragma unroll
        for (int j = 0; j < 16; ++j) buf[(t + 1 + j) & 15] += rk.k[j];
      }
      out[tid * 50 + t] = sp;
    }
  }
}

extern "C" void kernel_launch(void* const* d_in, const int* in_sizes, int n_in,
                              void* d_out, int out_size, void* d_ws, size_t ws_size,
                              hipStream_t stream) {
  const float* xin = (const float*)d_in[0];  // [4,2,256,256,50]
  const float* w1  = (const float*)d_in[1];  // [8,2,5,5]
  const float* w2  = (const float*)d_in[2];  // [16,8,3,3]
  const float* w3  = (const float*)d_in[3];  // [32,16,3,3]
  const float* wfc = (const float*)d_in[4];  // [2,32,8,8]
  float* out = (float*)d_out;                // [4,2,1,1,50]

  float* R0 = (float*)d_ws;                  // 26,214,400 floats
  float* R1 = R0 + 26214400;

  K32 pk;
  for (int k = 0; k < 32; ++k)
    pk.k[k] = (float)(((double)k / 10.0) * exp(1.0 - (double)k / 10.0));
  K16 rk;
  for (int j = 0; j < 16; ++j) {
    const double tr = (double)(j + 1);
    rk.k[j] = (float)(-2.0 * 10.0 * tr * exp(1.0 - tr));
  }

  // 1. psp1: xin -> R0 = u1 (524288 rows)
  psp_kernel<<<8192, 128, 0, stream>>>(xin, R0, 524288, pk);
  // 2. FUSED conv1+spike1+psp2+pool1+spike2: R0 -> R1 = s2 [4,8,63,63,50]
  conv_pps_kernel<2, 8, 5, 256, 256, 127, 127, 63, 63>
      <<<4 * 63 * 16, 256, 0, stream>>>(R0, w1, R1, pk, rk);
  // 3. FUSED conv2+psp3+spike3: R1 -> R0 = s3 [4,16,32,32,50]
  conv_fir_spike_kernel<8, 16, 3, 1, 63, 63, 32, 32>
      <<<4 * 32 * 8, 256, 0, stream>>>(R1, w2, R0, pk, rk);
  // 4. FUSED pool2+psp4+spike4: R0 -> R1 = s4 [4,16,16,16,50]
  pool_fir_spike_kernel<<<4 * 16 * 16, 128, 0, stream>>>(R0, R1, 32, 32, 16, 16, pk, rk);
  // 5. FUSED conv3+psp5+spike5: R1 -> R0 = s5 [4,32,8,8,50]
  conv_fir_spike_kernel<16, 32, 3, 1, 16, 16, 8, 8>
      <<<4 * 8 * 2, 256, 0, stream>>>(R1, w3, R0, pk, rk);
  // 6. FUSED fc+psp6+final spike: R0 -> out
  fc_fir_spike_kernel<<<1, 512, 0, stream>>>(wfc, R0, out, pk, rk);
}

// Round 4
// 479.333 us; speedup vs baseline: 1.2177x; 1.0071x over previous
//
#include <hip/hip_runtime.h>
#include <cmath>

struct K32 { float k[32]; };
struct K16 { float k[16]; };

#define THETA 10.0f

// ---------------- psp v8: 64 rows / 128 threads, balanced split at t=32 ----------------
__global__ __launch_bounds__(128)
void psp_kernel(const float* __restrict__ in, float* __restrict__ out,
                int nrows, K32 pk) {
  __shared__ __align__(16) float lds[64 * 50];
  const int rowBase = blockIdx.x * 64;
  const int tid = threadIdx.x;
  const int vr = min(64, nrows - rowBase);   // always even here
  const int n4 = (vr * 50) >> 2;
  const float4* g4 = (const float4*)(in + (size_t)rowBase * 50);
  for (int i = tid; i < n4; i += 128) *(float4*)(&lds[4 * i]) = g4[i];
  __syncthreads();
  const int r = tid & 63;
  const int part = tid >> 6;
  const bool act = r < vr;
  float x[50];
  if (act) {
    if (part == 0) {
#pragma unroll
      for (int t = 0; t < 32; ++t) x[t] = lds[r * 50 + t];
    } else {
#pragma unroll
      for (int t = 0; t < 50; ++t) x[t] = lds[r * 50 + t];
    }
  }
  __syncthreads();
  if (act) {
    if (part == 0) {
#pragma unroll
      for (int t = 0; t < 32; ++t) {
        float a = 0.f;
#pragma unroll
        for (int k = 31; k >= 0; --k)          // x-index ascending (oldest first)
          if (t - k >= 0) a += x[t - k] * pk.k[k];
        lds[r * 50 + t] = a;
      }
    } else {
#pragma unroll
      for (int t = 32; t < 50; ++t) {
        float a = 0.f;
#pragma unroll
        for (int k = 31; k >= 0; --k)
          a += x[t - k] * pk.k[k];             // t-k >= 1 always valid
        lds[r * 50 + t] = a;
      }
    }
  }
  __syncthreads();
  float4* o4 = (float4*)(out + (size_t)rowBase * 50);
  for (int i = tid; i < n4; i += 128) o4[i] = *(const float4*)(&lds[4 * i]);
}

// ====== L1 (R3-proven, untouched): conv1+spike1+psp2+pool1+spike2 ======
template <int CIN, int COUT, int KK, int HIN, int WIN, int S1H, int S1W,
          int S2H, int S2W>
__global__ __launch_bounds__(256)
void conv_pps_kernel(const float* __restrict__ x, const float* __restrict__ w,
                     float* __restrict__ s2out, K32 pk, K16 rk) {
  constexpr int WT = 4;                       // s1-wo per wave
  constexpr int SW = 8;                       // s1-wo per block
  constexpr int XR = 2 * (WT - 1) + KK;       // 11
  constexpr int GROUPS = (S1W + SW - 1) / SW; // 16
  constexpr int NROW = COUT * 2 * SW;         // 128
  __shared__ float lds[NROW * 51];            // 26 KB
  const int tid = threadIdx.x;
  const int wave = tid >> 6;
  const int lane = tid & 63;
  const int group = blockIdx.x % GROUPS;
  const int rest = blockIdx.x / GROUPS;
  const int hop = rest % S2H;                 // s2 ho
  const int n = rest / S2H;
  const int ho_off = wave & 1;
  const int wo_half = wave >> 1;
  const int ho = 2 * hop + ho_off;            // s1 ho
  const int wo0 = group * SW + wo_half * WT;
  const int tt = lane < 50 ? lane : 49;

  // ---- conv (checked loads, proven order c -> kh -> co -> kw -> wl) ----
  float acc[COUT][WT] = {};
  for (int c = 0; c < CIN; ++c) {
#pragma unroll
    for (int kh = 0; kh < KK; ++kh) {
      const int hi = 2 * ho + kh - 1;
      if ((unsigned)hi >= (unsigned)HIN) continue;   // zero padding
      float xr[XR];
#pragma unroll
      for (int i = 0; i < XR; ++i) {
        const int wi = 2 * wo0 - 1 + i;
        xr[i] = ((unsigned)wi < (unsigned)WIN)
                    ? x[(((size_t)(n * CIN + c) * HIN + hi) * WIN + wi) * 50 + tt]
                    : 0.f;
      }
#pragma unroll
      for (int co = 0; co < COUT; ++co)
#pragma unroll
        for (int kw = 0; kw < KK; ++kw) {
          const float wv = w[((co * CIN + c) * KK + kh) * KK + kw];
#pragma unroll
          for (int wl = 0; wl < WT; ++wl)
            acc[co][wl] += xr[2 * wl + kw] * wv;
        }
    }
  }
  // ---- transpose: LDS row = co*16 + ho_off*8 + wol ----
  if (lane < 50) {
#pragma unroll
    for (int co = 0; co < COUT; ++co)
#pragma unroll
      for (int wl = 0; wl < WT; ++wl)
        lds[((co * 2 + ho_off) * SW + wo_half * WT + wl) * 51 + lane] = acc[co][wl];
  }
  __syncthreads();
  // ---- FUSED spike1 + FIR(psp2): 2 threads/row, register-resident ----
  {
    const int r = tid & (NROW - 1);
    const int part = tid >> 7;                // 0: y[0..31], 1: y[32..49]
    const int wol = r & (SW - 1);
    const bool act = (group * SW + wol) < S1W;
    float xs[50];
    if (act) {
      if (part == 0) {
#pragma unroll
        for (int t = 0; t < 32; ++t) xs[t] = lds[r * 51 + t];
      } else {
#pragma unroll
        for (int t = 0; t < 50; ++t) xs[t] = lds[r * 51 + t];
      }
    }
    __syncthreads();                          // all reads done before any FIR write
    if (act) {
      if (part == 0) {
        float buf[16];
#pragma unroll
        for (int j = 0; j < 16; ++j) buf[j] = 0.f;
#pragma unroll
        for (int t = 0; t < 32; ++t) {        // spike in regs (t 0..31 suffices)
          float v = xs[t] + buf[t & 15];
          buf[t & 15] = 0.f;
          float sp = 0.f;
          if (v >= THETA) {
            sp = 1.f;
#pragma unroll
            for (int j = 0; j < 16; ++j) buf[(t + 1 + j) & 15] += rk.k[j];
          }
          xs[t] = sp;
        }
#pragma unroll
        for (int t = 0; t < 32; ++t) {        // FIR y[0..31]
          float a = 0.f;
#pragma unroll
          for (int k = 31; k >= 0; --k)
            if (t - k >= 0) a += xs[t - k] * pk.k[k];
          lds[r * 51 + t] = a;
        }
      } else {
        float buf[16];
#pragma unroll
        for (int j = 0; j < 16; ++j) buf[j] = 0.f;
#pragma unroll
        for (int t = 0; t < 50; ++t) {        // spike in regs (full row)
          float v = xs[t] + buf[t & 15];
          buf[t & 15] = 0.f;
          float sp = 0.f;
          if (v >= THETA) {
            sp = 1.f;
#pragma unroll
            for (int j = 0; j < 16; ++j) buf[(t + 1 + j) & 15] += rk.k[j];
          }
          xs[t] = sp;
        }
#pragma unroll
        for (int t = 32; t < 50; ++t) {       // FIR y[32..49], all 32 taps valid
          float a = 0.f;
#pragma unroll
          for (int k = 31; k >= 0; --k)
            a += xs[t - k] * pk.k[k];
          lds[r * 51 + t] = a;
        }
      }
    }
  }
  __syncthreads();
  // ---- pool ((h0w0+h0w1)+h1w0)+h1w1 * 2.75 -> spike -> direct store ----
  if (tid < COUT * (SW / 2)) {                // 32 threads
    const int co = tid / (SW / 2);
    const int wpl = tid % (SW / 2);
    const int wop = group * (SW / 2) + wpl;   // s2 wo
    if (wop < S2W) {
      const int r00 = (co * 16 + 2 * wpl) * 51;
      const int r01 = (co * 16 + 2 * wpl + 1) * 51;
      const int r10 = (co * 16 + 8 + 2 * wpl) * 51;
      const int r11 = (co * 16 + 8 + 2 * wpl + 1) * 51;
      float* orow = s2out + (((size_t)(n * COUT + co) * S2H + hop) * S2W + wop) * 50;
      float buf[16];
#pragma unroll
      for (int j = 0; j < 16; ++j) buf[j] = 0.f;
      float prev = 0.f;
#pragma unroll
      for (int t = 0; t < 50; ++t) {
        const float u0 = (((lds[r00 + t] + lds[r01 + t]) + lds[r10 + t]) + lds[r11 + t]) * 2.75f;
        float v = u0 + buf[t & 15];
        buf[t & 15] = 0.f;
        float sp = 0.f;
        if (v >= THETA) {
          sp = 1.f;
#pragma unroll
          for (int j = 0; j < 16; ++j) buf[(t + 1 + j) & 15] += rk.k[j];
        }
        if (t & 1) *(float2*)(orow + t - 1) = make_float2(prev, sp);
        else prev = sp;
      }
    }
  }
}

// ====== NEW (R4) L2 MERGED: conv2 + psp3(FIR) + spike3 + pool2 + psp4(FIR) + spike4 ======
// Replaces conv_fir_spike(L2) + pool_fir_spike and the s3 global round-trip.
// Phase order (psp3 commuted in, so FIR precedes spike): conv(raw s2 spikes) ->
// FIR(psp3) on 128 conv rows -> spike3 in-place -> pool-sum -> FIR(psp4) on 32
// pooled rows -> spike4 -> store. Every phase is op-for-op identical to the
// verified conv_fir_spike / pool_fir_spike kernels.
template <int CIN, int COUT, int KK, int SW, int WT, int HIN, int WIN,
          int S1H, int S1W, int S2H, int S2W>
__global__ __launch_bounds__(256)
void conv_pps2_kernel(const float* __restrict__ x, const float* __restrict__ w,
                      float* __restrict__ s2out, K32 pk, K16 rk) {
  constexpr int XR = 2 * (WT - 1) + KK;       // 5
  constexpr int GROUPS = (S1W + SW - 1) / SW; // 8
  constexpr int NROW = COUT * 2 * SW;         // 128
  constexpr int NROWP = COUT * (SW / 2);      // 32 pooled rows
  __shared__ float lds[NROW * 51];            // 26 KB
  const int tid = threadIdx.x;
  const int wave = tid >> 6;
  const int lane = tid & 63;
  const int group = blockIdx.x % GROUPS;
  const int rest = blockIdx.x / GROUPS;
  const int hop = rest % S2H;                 // s2 ho
  const int n = rest / S2H;
  const int ho_off = wave & 1;
  const int wo_half = wave >> 1;
  const int ho = 2 * hop + ho_off;            // s1 ho
  const int wo0 = group * SW + wo_half * WT;
  const int tt = lane < 50 ? lane : 49;

  // ---- conv on raw s2 spikes (order c -> kh -> co -> kw -> wl) ----
  float acc[COUT][WT] = {};
  for (int c = 0; c < CIN; ++c) {
#pragma unroll
    for (int kh = 0; kh < KK; ++kh) {
      const int hi = 2 * ho + kh - 1;
      if ((unsigned)hi >= (unsigned)HIN) continue;   // zero padding
      float xr[XR];
#pragma unroll
      for (int i = 0; i < XR; ++i) {
        const int wi = 2 * wo0 - 1 + i;
        xr[i] = ((unsigned)wi < (unsigned)WIN)
                    ? x[(((size_t)(n * CIN + c) * HIN + hi) * WIN + wi) * 50 + tt]
                    : 0.f;
      }
#pragma unroll
      for (int co = 0; co < COUT; ++co)
#pragma unroll
        for (int kw = 0; kw < KK; ++kw) {
          const float wv = w[((co * CIN + c) * KK + kh) * KK + kw];
#pragma unroll
          for (int wl = 0; wl < WT; ++wl)
            acc[co][wl] += xr[2 * wl + kw] * wv;
        }
    }
  }
  // ---- transpose: LDS row = (co*2 + ho_off)*SW + wol ----
  if (lane < 50) {
#pragma unroll
    for (int co = 0; co < COUT; ++co)
#pragma unroll
      for (int wl = 0; wl < WT; ++wl)
        lds[((co * 2 + ho_off) * SW + wo_half * WT + wl) * 51 + lane] = acc[co][wl];
  }
  __syncthreads();
  // ---- FIR (psp3) on 128 conv rows: 2 thr/row, snapshot -> barrier -> in-place ----
  {
    const int r = tid & (NROW - 1);
    const int part = tid >> 7;                // 0: y[0..31], 1: y[32..49]
    float xs[50];
    if (part == 0) {
#pragma unroll
      for (int t = 0; t < 32; ++t) xs[t] = lds[r * 51 + t];
    } else {
#pragma unroll
      for (int t = 0; t < 50; ++t) xs[t] = lds[r * 51 + t];
    }
    __syncthreads();
    if (part == 0) {
#pragma unroll
      for (int t = 0; t < 32; ++t) {
        float a = 0.f;
#pragma unroll
        for (int k = 31; k >= 0; --k)
          if (t - k >= 0) a += xs[t - k] * pk.k[k];
        lds[r * 51 + t] = a;
      }
    } else {
#pragma unroll
      for (int t = 32; t < 50; ++t) {
        float a = 0.f;
#pragma unroll
        for (int k = 31; k >= 0; --k)
          a += xs[t - k] * pk.k[k];            // all taps valid for t >= 32
        lds[r * 51 + t] = a;
      }
    }
  }
  __syncthreads();
  // ---- spike3 per row (128 rows, in place) ----
  if (tid < NROW) {
    float buf[16];
#pragma unroll
    for (int j = 0; j < 16; ++j) buf[j] = 0.f;
#pragma unroll
    for (int t = 0; t < 50; ++t) {
      float v = lds[tid * 51 + t] + buf[t & 15];
      buf[t & 15] = 0.f;
      float sp = 0.f;
      if (v >= THETA) {
        sp = 1.f;
#pragma unroll
        for (int j = 0; j < 16; ++j) buf[(t + 1 + j) & 15] += rk.k[j];
      }
      lds[tid * 51 + t] = sp;
    }
  }
  __syncthreads();
  // ---- pool-sum + FIR (psp4) on 32 pooled rows: 2 thr/row ----
  {
    const int r = tid & (NROWP - 1);
    const int part = tid >> 5;                // 0..7, only part<2 active
    const bool act = part < 2;
    const int co = r / (SW / 2);
    const int wpl = r % (SW / 2);
    const int r00 = ((co * 2) * SW + 2 * wpl) * 51;
    const int r01 = r00 + 51;
    const int r10 = ((co * 2 + 1) * SW + 2 * wpl) * 51;
    const int r11 = r10 + 51;
    float xs[50];
    if (act) {
      if (part == 0) {
#pragma unroll
        for (int t = 0; t < 32; ++t)
          xs[t] = (((lds[r00 + t] + lds[r01 + t]) + lds[r10 + t]) + lds[r11 + t]) * 2.75f;
      } else {
#pragma unroll
        for (int t = 0; t < 50; ++t)
          xs[t] = (((lds[r00 + t] + lds[r01 + t]) + lds[r10 + t]) + lds[r11 + t]) * 2.75f;
      }
    }
    __syncthreads();
    if (act) {
      if (part == 0) {
#pragma unroll
        for (int t = 0; t < 32; ++t) {
          float a = 0.f;
#pragma unroll
          for (int k = 31; k >= 0; --k)
            if (t - k >= 0) a += xs[t - k] * pk.k[k];
          lds[r00 + t] = a;
        }
      } else {
#pragma unroll
        for (int t = 32; t < 50; ++t) {
          float a = 0.f;
#pragma unroll
          for (int k = 31; k >= 0; --k)
            a += xs[t - k] * pk.k[k];
          lds[r00 + t] = a;
        }
      }
    }
  }
  __syncthreads();
  // ---- spike4 -> direct store ----
  if (tid < NROWP) {
    const int co = tid / (SW / 2);
    const int wpl = tid % (SW / 2);
    const int wop = group * (SW / 2) + wpl;   // s2 wo
    if (wop < S2W) {
      const int r00 = ((co * 2) * SW + 2 * wpl) * 51;
      float* orow = s2out + (((size_t)(n * COUT + co) * S2H + hop) * S2W + wop) * 50;
      float buf[16];
#pragma unroll
      for (int j = 0; j < 16; ++j) buf[j] = 0.f;
      float prev = 0.f;
#pragma unroll
      for (int t = 0; t < 50; ++t) {
        float v = lds[r00 + t] + buf[t & 15];
        buf[t & 15] = 0.f;
        float sp = 0.f;
        if (v >= THETA) {
          sp = 1.f;
#pragma unroll
          for (int j = 0; j < 16; ++j) buf[(t + 1 + j) & 15] += rk.k[j];
        }
        if (t & 1) *(float2*)(orow + t - 1) = make_float2(prev, sp);
        else prev = sp;
      }
    }
  }
}

// ====== fused conv (stride2,pad1) + psp(commuted) + spike (verified, L3 only) ======
template <int CIN, int COUT, int KK, int WT, int HIN, int WIN, int HOUT, int WOUT>
__global__ __launch_bounds__(256)
void conv_fir_spike_kernel(const float* __restrict__ x, const float* __restrict__ w,
                           float* __restrict__ s, K32 pk, K16 rk) {
  constexpr int XR = 2 * (WT - 1) + KK;
  constexpr int TW = 4 * WT;                 // wo span per block (4 waves)
  constexpr int GROUPS = (WOUT + TW - 1) / TW;
  constexpr int NROW = COUT * TW;
  __shared__ float lds[NROW * 51];
  const int tid = threadIdx.x;
  const int wave = tid >> 6;
  const int lane = tid & 63;
  const int group = blockIdx.x % GROUPS;
  const int rest = blockIdx.x / GROUPS;
  const int ho = rest % HOUT;
  const int n = rest / HOUT;
  const int wo0 = group * TW + wave * WT;
  const int tt = lane < 50 ? lane : 49;

  float acc[COUT][WT] = {};
  for (int c = 0; c < CIN; ++c) {
#pragma unroll
    for (int kh = 0; kh < KK; ++kh) {
      const int hi = 2 * ho + kh - 1;
      if ((unsigned)hi >= (unsigned)HIN) continue;   // zero padding
      float xr[XR];
#pragma unroll
      for (int i = 0; i < XR; ++i) {
        const int wi = 2 * wo0 - 1 + i;
        xr[i] = ((unsigned)wi < (unsigned)WIN)
                    ? x[(((size_t)(n * CIN + c) * HIN + hi) * WIN + wi) * 50 + tt]
                    : 0.f;
      }
#pragma unroll
      for (int co = 0; co < COUT; ++co)
#pragma unroll
        for (int kw = 0; kw < KK; ++kw) {
          const float wv = w[((co * CIN + c) * KK + kh) * KK + kw];
#pragma unroll
          for (int wl = 0; wl < WT; ++wl)
            acc[co][wl] += xr[2 * wl + kw] * wv;
        }
    }
  }

  if (lane < 50) {
#pragma unroll
    for (int co = 0; co < COUT; ++co)
#pragma unroll
      for (int wl = 0; wl < WT; ++wl)
        lds[(co * TW + wave * WT + wl) * 51 + lane] = acc[co][wl];
  }
  __syncthreads();
  // ---- FIR = psp (commuted past conv): 2 threads/row ----
  {
    const int r = tid % NROW;
    const int part = tid / NROW;
    const int wol = r % TW;
    const bool act = (part < 2) && (group * TW + wol < WOUT);
    float xs[50];
    if (act) {
      if (part == 0) {
#pragma unroll
        for (int t = 0; t < 25; ++t) xs[t] = lds[r * 51 + t];
      } else {
#pragma unroll
        for (int t = 0; t < 50; ++t) xs[t] = lds[r * 51 + t];
      }
    }
    __syncthreads();
    if (act) {
      if (part == 0) {
#pragma unroll
        for (int t = 0; t < 25; ++t) {
          float a = 0.f;
#pragma unroll
          for (int k = 31; k >= 0; --k)
            if (t - k >= 0) a += xs[t - k] * pk.k[k];
          lds[r * 51 + t] = a;
        }
      } else {
#pragma unroll
        for (int t = 25; t < 50; ++t) {
          float a = 0.f;
#pragma unroll
          for (int k = 31; k >= 0; --k)
            if (t - k >= 0) a += xs[t - k] * pk.k[k];
          lds[r * 51 + t] = a;
        }
      }
    }
  }
  __syncthreads();
  // spike along t, one thread per output row, direct float2 store from regs
  if (tid < NROW) {
    const int co = tid / TW;
    const int wol = tid - co * TW;
    const int wo = group * TW + wol;
    if (wo < WOUT) {
      float* orow = s + (((size_t)(n * COUT + co) * HOUT + ho) * WOUT + wo) * 50;
      float buf[16];
#pragma unroll
      for (int j = 0; j < 16; ++j) buf[j] = 0.f;
      float prev = 0.f;
#pragma unroll
      for (int t = 0; t < 50; ++t) {
        float v = lds[tid * 51 + t] + buf[t & 15];
        buf[t & 15] = 0.f;
        float sp = 0.f;
        if (v >= THETA) {
          sp = 1.f;
#pragma unroll
          for (int j = 0; j < 16; ++j) buf[(t + 1 + j) & 15] += rk.k[j];
        }
        if (t & 1) *(float2*)(orow + t - 1) = make_float2(prev, sp);
        else prev = sp;
      }
    }
  }
}

// ====== fc + psp(commuted) + final spike (verified) ======
__global__ __launch_bounds__(512)
void fc_fir_spike_kernel(const float* __restrict__ w, const float* __restrict__ s,
                         float* __restrict__ out, K32 pk, K16 rk) {
  __shared__ float lds[8 * 51];
  const int tid = threadIdx.x;
  const int wave = tid >> 6, lane = tid & 63;
  const int o = wave & 1, n = wave >> 1;
  const int tt = lane < 50 ? lane : 49;
  const float* wrow = w + (size_t)o * 2048;
  const float* ub = s + (size_t)n * 2048 * 50;
  float acc = 0.f;
#pragma unroll 32
  for (int i = 0; i < 2048; ++i) acc += wrow[i] * ub[(size_t)i * 50 + tt];
  if (lane < 50) lds[wave * 51 + lane] = acc;
  __syncthreads();
  // ---- FIR = psp6 (commuted past einsum): 2 threads/row, in place ----
  {
    const int r = tid & 7;
    const int part = tid >> 3;      // only part<2 active
    const bool act = part < 2;
    float xs[50];
    if (act) {
      if (part == 0) {
#pragma unroll
        for (int t = 0; t < 25; ++t) xs[t] = lds[r * 51 + t];
      } else {
#pragma unroll
        for (int t = 0; t < 50; ++t) xs[t] = lds[r * 51 + t];
      }
    }
    __syncthreads();
    if (act) {
      if (part == 0) {
#pragma unroll
        for (int t = 0; t < 25; ++t) {
          float a = 0.f;
#pragma unroll
          for (int k = 31; k >= 0; --k)
            if (t - k >= 0) a += xs[t - k] * pk.k[k];
          lds[r * 51 + t] = a;
        }
      } else {
#pragma unroll
        for (int t = 25; t < 50; ++t) {
          float a = 0.f;
#pragma unroll
          for (int k = 31; k >= 0; --k)
            if (t - k >= 0) a += xs[t - k] * pk.k[k];
          lds[r * 51 + t] = a;
        }
      }
    }
  }
  __syncthreads();
  if (tid < 8) {
    float buf[16];
#pragma unroll
    for (int j = 0; j < 16; ++j) buf[j] = 0.f;
#pragma unroll
    for (int t = 0; t < 50; ++t) {
      float v = lds[tid * 51 + t] + buf[t & 15];
      buf[t & 15] = 0.f;
      float sp = 0.f;
      if (v >= THETA) {
        sp = 1.f;
#pragma unroll
        for (int j = 0; j < 16; ++j) buf[(t + 1 + j) & 15] += rk.k[j];
      }
      out[tid * 50 + t] = sp;
    }
  }
}

extern "C" void kernel_launch(void* const* d_in, const int* in_sizes, int n_in,
                              void* d_out, int out_size, void* d_ws, size_t ws_size,
                              hipStream_t stream) {
  const float* xin = (const float*)d_in[0];  // [4,2,256,256,50]
  const float* w1  = (const float*)d_in[1];  // [8,2,5,5]
  const float* w2  = (const float*)d_in[2];  // [16,8,3,3]
  const float* w3  = (const float*)d_in[3];  // [32,16,3,3]
  const float* wfc = (const float*)d_in[4];  // [2,32,8,8]
  float* out = (float*)d_out;                // [4,2,1,1,50]

  float* R0 = (float*)d_ws;                  // 26,214,400 floats
  float* R1 = R0 + 26214400;

  K32 pk;
  for (int k = 0; k < 32; ++k)
    pk.k[k] = (float)(((double)k / 10.0) * exp(1.0 - (double)k / 10.0));
  K16 rk;
  for (int j = 0; j < 16; ++j) {
    const double tr = (double)(j + 1);
    rk.k[j] = (float)(-2.0 * 10.0 * tr * exp(1.0 - tr));
  }

  // 1. psp1: xin -> R0 = u1 (524288 rows)
  psp_kernel<<<8192, 128, 0, stream>>>(xin, R0, 524288, pk);
  // 2. FUSED conv1+spike1+psp2+pool1+spike2: R0 -> R1 = s2 [4,8,63,63,50]
  conv_pps_kernel<2, 8, 5, 256, 256, 127, 127, 63, 63>
      <<<4 * 63 * 16, 256, 0, stream>>>(R0, w1, R1, pk, rk);
  // 3. MERGED L2: conv2+psp3+spike3+pool2+psp4+spike4: R1 -> R0 = s4 [4,16,16,16,50]
  //    SW=4, WT=2: grid = 4 n * 16 s2ho * 8 groups = 512
  conv_pps2_kernel<8, 16, 3, 4, 2, 63, 63, 32, 32, 16, 16>
      <<<4 * 16 * 8, 256, 0, stream>>>(R1, w2, R0, pk, rk);
  // 4. FUSED conv3+psp5+spike5: R0 -> R1 = s5 [4,32,8,8,50]
  conv_fir_spike_kernel<16, 32, 3, 1, 16, 16, 8, 8>
      <<<4 * 8 * 2, 256, 0, stream>>>(R0, w3, R1, pk, rk);
  // 5. FUSED fc+psp6+final spike: R1 -> out
  fc_fir_spike_kernel<<<1, 512, 0, stream>>>(wfc, R1, out, pk, rk);
}

// Round 5
// 464.761 us; speedup vs baseline: 1.2559x; 1.0314x over previous
//
#include <hip/hip_runtime.h>
#include <cmath>

struct K32 { float k[32]; };
struct K16 { float k[16]; };

#define THETA 10.0f

// ====== L1 FULLY FUSED (R5): conv1(raw x) + psp1(FIR,commuted) + spike1 +
//        psp2(FIR) + pool1 + spike2  ->  s2  ======
// Reference: spike(pool(psp(spike(conv(psp(x)))))) == (psp commutes w/ conv)
// spike(pool(psp(spike(psp_on_convout(conv(x)))))). FIR1 runs in registers
// inside the proven fused phase; split rebalanced at T0=39 (part0 handles
// t<39 end-to-end, part1 computes full prefix + t>=39 outputs).
template <int CIN, int COUT, int KK, int HIN, int WIN, int S1H, int S1W,
          int S2H, int S2W>
__global__ __launch_bounds__(256)
void conv_pps_kernel(const float* __restrict__ x, const float* __restrict__ w,
                     float* __restrict__ s2out, K32 pk, K16 rk) {
  constexpr int WT = 4;                       // s1-wo per wave
  constexpr int SW = 8;                       // s1-wo per block
  constexpr int XR = 2 * (WT - 1) + KK;       // 11
  constexpr int GROUPS = (S1W + SW - 1) / SW; // 16
  constexpr int NROW = COUT * 2 * SW;         // 128
  constexpr int T0 = 39;                      // balanced part split
  __shared__ float lds[NROW * 51];            // 26 KB
  const int tid = threadIdx.x;
  const int wave = tid >> 6;
  const int lane = tid & 63;
  const int group = blockIdx.x % GROUPS;
  const int rest = blockIdx.x / GROUPS;
  const int hop = rest % S2H;                 // s2 ho
  const int n = rest / S2H;
  const int ho_off = wave & 1;
  const int wo_half = wave >> 1;
  const int ho = 2 * hop + ho_off;            // s1 ho
  const int wo0 = group * SW + wo_half * WT;
  const int tt = lane < 50 ? lane : 49;

  // ---- conv on RAW binary spikes (proven order c -> kh -> co -> kw -> wl) ----
  float acc[COUT][WT] = {};
  for (int c = 0; c < CIN; ++c) {
#pragma unroll
    for (int kh = 0; kh < KK; ++kh) {
      const int hi = 2 * ho + kh - 1;
      if ((unsigned)hi >= (unsigned)HIN) continue;   // zero padding
      float xr[XR];
#pragma unroll
      for (int i = 0; i < XR; ++i) {
        const int wi = 2 * wo0 - 1 + i;
        xr[i] = ((unsigned)wi < (unsigned)WIN)
                    ? x[(((size_t)(n * CIN + c) * HIN + hi) * WIN + wi) * 50 + tt]
                    : 0.f;
      }
#pragma unroll
      for (int co = 0; co < COUT; ++co)
#pragma unroll
        for (int kw = 0; kw < KK; ++kw) {
          const float wv = w[((co * CIN + c) * KK + kh) * KK + kw];
#pragma unroll
          for (int wl = 0; wl < WT; ++wl)
            acc[co][wl] += xr[2 * wl + kw] * wv;
        }
    }
  }
  // ---- transpose: LDS row = co*16 + ho_off*8 + wol ----
  if (lane < 50) {
#pragma unroll
    for (int co = 0; co < COUT; ++co)
#pragma unroll
      for (int wl = 0; wl < WT; ++wl)
        lds[((co * 2 + ho_off) * SW + wo_half * WT + wl) * 51 + lane] = acc[co][wl];
  }
  __syncthreads();
  // ---- FUSED FIR1(psp1) + spike1 + FIR2(psp2): 2 threads/row, registers ----
  {
    const int r = tid & (NROW - 1);
    const int part = tid >> 7;                // 0: y[0..T0), 1: y[T0..49]
    const int wol = r & (SW - 1);
    const bool act = (group * SW + wol) < S1W;
    float xs[50];                             // conv output c
    if (act) {
      if (part == 0) {
#pragma unroll
        for (int t = 0; t < T0; ++t) xs[t] = lds[r * 51 + t];
      } else {
#pragma unroll
        for (int t = 0; t < 50; ++t) xs[t] = lds[r * 51 + t];
      }
    }
    __syncthreads();                          // all reads done before any FIR write
    if (act) {
      if (part == 0) {
        float us[T0];
#pragma unroll
        for (int t = 0; t < 32; ++t) {        // FIR1: u[0..31] (guarded taps)
          float a = 0.f;
#pragma unroll
          for (int k = 31; k >= 0; --k)
            if (t - k >= 0) a += xs[t - k] * pk.k[k];
          us[t] = a;
        }
#pragma unroll
        for (int t = 32; t < T0; ++t) {       // FIR1: u[32..38] (all taps valid)
          float a = 0.f;
#pragma unroll
          for (int k = 31; k >= 0; --k)
            a += xs[t - k] * pk.k[k];
          us[t] = a;
        }
        float buf[16];
#pragma unroll
        for (int j = 0; j < 16; ++j) buf[j] = 0.f;
#pragma unroll
        for (int t = 0; t < T0; ++t) {        // spike1 in regs, overwrite us
          float v = us[t] + buf[t & 15];
          buf[t & 15] = 0.f;
          float sp = 0.f;
          if (v >= THETA) {
            sp = 1.f;
#pragma unroll
            for (int j = 0; j < 16; ++j) buf[(t + 1 + j) & 15] += rk.k[j];
          }
          us[t] = sp;
        }
#pragma unroll
        for (int t = 0; t < 32; ++t) {        // FIR2: y[0..31] (guarded)
          float a = 0.f;
#pragma unroll
          for (int k = 31; k >= 0; --k)
            if (t - k >= 0) a += us[t - k] * pk.k[k];
          lds[r * 51 + t] = a;
        }
#pragma unroll
        for (int t = 32; t < T0; ++t) {       // FIR2: y[32..38] (all taps valid)
          float a = 0.f;
#pragma unroll
          for (int k = 31; k >= 0; --k)
            a += us[t - k] * pk.k[k];
          lds[r * 51 + t] = a;
        }
      } else {
        float us[50];
#pragma unroll
        for (int t = 0; t < 32; ++t) {        // FIR1 full prefix (guarded)
          float a = 0.f;
#pragma unroll
          for (int k = 31; k >= 0; --k)
            if (t - k >= 0) a += xs[t - k] * pk.k[k];
          us[t] = a;
        }
#pragma unroll
        for (int t = 32; t < 50; ++t) {       // FIR1 (all taps valid)
          float a = 0.f;
#pragma unroll
          for (int k = 31; k >= 0; --k)
            a += xs[t - k] * pk.k[k];
          us[t] = a;
        }
        float buf[16];
#pragma unroll
        for (int j = 0; j < 16; ++j) buf[j] = 0.f;
#pragma unroll
        for (int t = 0; t < 50; ++t) {        // spike1 full row, overwrite us
          float v = us[t] + buf[t & 15];
          buf[t & 15] = 0.f;
          float sp = 0.f;
          if (v >= THETA) {
            sp = 1.f;
#pragma unroll
            for (int j = 0; j < 16; ++j) buf[(t + 1 + j) & 15] += rk.k[j];
          }
          us[t] = sp;
        }
#pragma unroll
        for (int t = T0; t < 50; ++t) {       // FIR2: y[39..49] (all taps valid)
          float a = 0.f;
#pragma unroll
          for (int k = 31; k >= 0; --k)
            a += us[t - k] * pk.k[k];
          lds[r * 51 + t] = a;
        }
      }
    }
  }
  __syncthreads();
  // ---- pool ((h0w0+h0w1)+h1w0)+h1w1 * 2.75 -> spike -> direct store ----
  if (tid < COUT * (SW / 2)) {                // 32 threads
    const int co = tid / (SW / 2);
    const int wpl = tid % (SW / 2);
    const int wop = group * (SW / 2) + wpl;   // s2 wo
    if (wop < S2W) {
      const int r00 = (co * 16 + 2 * wpl) * 51;
      const int r01 = (co * 16 + 2 * wpl + 1) * 51;
      const int r10 = (co * 16 + 8 + 2 * wpl) * 51;
      const int r11 = (co * 16 + 8 + 2 * wpl + 1) * 51;
      float* orow = s2out + (((size_t)(n * COUT + co) * S2H + hop) * S2W + wop) * 50;
      float buf[16];
#pragma unroll
      for (int j = 0; j < 16; ++j) buf[j] = 0.f;
      float prev = 0.f;
#pragma unroll
      for (int t = 0; t < 50; ++t) {
        const float u0 = (((lds[r00 + t] + lds[r01 + t]) + lds[r10 + t]) + lds[r11 + t]) * 2.75f;
        float v = u0 + buf[t & 15];
        buf[t & 15] = 0.f;
        float sp = 0.f;
        if (v >= THETA) {
          sp = 1.f;
#pragma unroll
          for (int j = 0; j < 16; ++j) buf[(t + 1 + j) & 15] += rk.k[j];
        }
        if (t & 1) *(float2*)(orow + t - 1) = make_float2(prev, sp);
        else prev = sp;
      }
    }
  }
}

// ====== L2 MERGED (R4-proven): conv2 + psp3(FIR) + spike3 + pool2 + psp4(FIR) + spike4 ======
template <int CIN, int COUT, int KK, int SW, int WT, int HIN, int WIN,
          int S1H, int S1W, int S2H, int S2W>
__global__ __launch_bounds__(256)
void conv_pps2_kernel(const float* __restrict__ x, const float* __restrict__ w,
                      float* __restrict__ s2out, K32 pk, K16 rk) {
  constexpr int XR = 2 * (WT - 1) + KK;       // 5
  constexpr int GROUPS = (S1W + SW - 1) / SW; // 8
  constexpr int NROW = COUT * 2 * SW;         // 128
  constexpr int NROWP = COUT * (SW / 2);      // 32 pooled rows
  __shared__ float lds[NROW * 51];            // 26 KB
  const int tid = threadIdx.x;
  const int wave = tid >> 6;
  const int lane = tid & 63;
  const int group = blockIdx.x % GROUPS;
  const int rest = blockIdx.x / GROUPS;
  const int hop = rest % S2H;                 // s2 ho
  const int n = rest / S2H;
  const int ho_off = wave & 1;
  const int wo_half = wave >> 1;
  const int ho = 2 * hop + ho_off;            // s1 ho
  const int wo0 = group * SW + wo_half * WT;
  const int tt = lane < 50 ? lane : 49;

  // ---- conv on raw s2 spikes (order c -> kh -> co -> kw -> wl) ----
  float acc[COUT][WT] = {};
  for (int c = 0; c < CIN; ++c) {
#pragma unroll
    for (int kh = 0; kh < KK; ++kh) {
      const int hi = 2 * ho + kh - 1;
      if ((unsigned)hi >= (unsigned)HIN) continue;   // zero padding
      float xr[XR];
#pragma unroll
      for (int i = 0; i < XR; ++i) {
        const int wi = 2 * wo0 - 1 + i;
        xr[i] = ((unsigned)wi < (unsigned)WIN)
                    ? x[(((size_t)(n * CIN + c) * HIN + hi) * WIN + wi) * 50 + tt]
                    : 0.f;
      }
#pragma unroll
      for (int co = 0; co < COUT; ++co)
#pragma unroll
        for (int kw = 0; kw < KK; ++kw) {
          const float wv = w[((co * CIN + c) * KK + kh) * KK + kw];
#pragma unroll
          for (int wl = 0; wl < WT; ++wl)
            acc[co][wl] += xr[2 * wl + kw] * wv;
        }
    }
  }
  // ---- transpose: LDS row = (co*2 + ho_off)*SW + wol ----
  if (lane < 50) {
#pragma unroll
    for (int co = 0; co < COUT; ++co)
#pragma unroll
      for (int wl = 0; wl < WT; ++wl)
        lds[((co * 2 + ho_off) * SW + wo_half * WT + wl) * 51 + lane] = acc[co][wl];
  }
  __syncthreads();
  // ---- FIR (psp3) on 128 conv rows: 2 thr/row, snapshot -> barrier -> in-place ----
  {
    const int r = tid & (NROW - 1);
    const int part = tid >> 7;                // 0: y[0..31], 1: y[32..49]
    float xs[50];
    if (part == 0) {
#pragma unroll
      for (int t = 0; t < 32; ++t) xs[t] = lds[r * 51 + t];
    } else {
#pragma unroll
      for (int t = 0; t < 50; ++t) xs[t] = lds[r * 51 + t];
    }
    __syncthreads();
    if (part == 0) {
#pragma unroll
      for (int t = 0; t < 32; ++t) {
        float a = 0.f;
#pragma unroll
        for (int k = 31; k >= 0; --k)
          if (t - k >= 0) a += xs[t - k] * pk.k[k];
        lds[r * 51 + t] = a;
      }
    } else {
#pragma unroll
      for (int t = 32; t < 50; ++t) {
        float a = 0.f;
#pragma unroll
        for (int k = 31; k >= 0; --k)
          a += xs[t - k] * pk.k[k];            // all taps valid for t >= 32
        lds[r * 51 + t] = a;
      }
    }
  }
  __syncthreads();
  // ---- spike3 per row (128 rows, in place) ----
  if (tid < NROW) {
    float buf[16];
#pragma unroll
    for (int j = 0; j < 16; ++j) buf[j] = 0.f;
#pragma unroll
    for (int t = 0; t < 50; ++t) {
      float v = lds[tid * 51 + t] + buf[t & 15];
      buf[t & 15] = 0.f;
      float sp = 0.f;
      if (v >= THETA) {
        sp = 1.f;
#pragma unroll
        for (int j = 0; j < 16; ++j) buf[(t + 1 + j) & 15] += rk.k[j];
      }
      lds[tid * 51 + t] = sp;
    }
  }
  __syncthreads();
  // ---- pool-sum + FIR (psp4) on 32 pooled rows: 2 thr/row ----
  {
    const int r = tid & (NROWP - 1);
    const int part = tid >> 5;                // 0..7, only part<2 active
    const bool act = part < 2;
    const int co = r / (SW / 2);
    const int wpl = r % (SW / 2);
    const int r00 = ((co * 2) * SW + 2 * wpl) * 51;
    const int r01 = r00 + 51;
    const int r10 = ((co * 2 + 1) * SW + 2 * wpl) * 51;
    const int r11 = r10 + 51;
    float xs[50];
    if (act) {
      if (part == 0) {
#pragma unroll
        for (int t = 0; t < 32; ++t)
          xs[t] = (((lds[r00 + t] + lds[r01 + t]) + lds[r10 + t]) + lds[r11 + t]) * 2.75f;
      } else {
#pragma unroll
        for (int t = 0; t < 50; ++t)
          xs[t] = (((lds[r00 + t] + lds[r01 + t]) + lds[r10 + t]) + lds[r11 + t]) * 2.75f;
      }
    }
    __syncthreads();
    if (act) {
      if (part == 0) {
#pragma unroll
        for (int t = 0; t < 32; ++t) {
          float a = 0.f;
#pragma unroll
          for (int k = 31; k >= 0; --k)
            if (t - k >= 0) a += xs[t - k] * pk.k[k];
          lds[r00 + t] = a;
        }
      } else {
#pragma unroll
        for (int t = 32; t < 50; ++t) {
          float a = 0.f;
#pragma unroll
          for (int k = 31; k >= 0; --k)
            a += xs[t - k] * pk.k[k];
          lds[r00 + t] = a;
        }
      }
    }
  }
  __syncthreads();
  // ---- spike4 -> direct store ----
  if (tid < NROWP) {
    const int co = tid / (SW / 2);
    const int wpl = tid % (SW / 2);
    const int wop = group * (SW / 2) + wpl;   // s2 wo
    if (wop < S2W) {
      const int r00 = ((co * 2) * SW + 2 * wpl) * 51;
      float* orow = s2out + (((size_t)(n * COUT + co) * S2H + hop) * S2W + wop) * 50;
      float buf[16];
#pragma unroll
      for (int j = 0; j < 16; ++j) buf[j] = 0.f;
      float prev = 0.f;
#pragma unroll
      for (int t = 0; t < 50; ++t) {
        float v = lds[r00 + t] + buf[t & 15];
        buf[t & 15] = 0.f;
        float sp = 0.f;
        if (v >= THETA) {
          sp = 1.f;
#pragma unroll
          for (int j = 0; j < 16; ++j) buf[(t + 1 + j) & 15] += rk.k[j];
        }
        if (t & 1) *(float2*)(orow + t - 1) = make_float2(prev, sp);
        else prev = sp;
      }
    }
  }
}

// ====== fused conv (stride2,pad1) + psp(commuted) + spike (verified, L3 only) ======
template <int CIN, int COUT, int KK, int WT, int HIN, int WIN, int HOUT, int WOUT>
__global__ __launch_bounds__(256)
void conv_fir_spike_kernel(const float* __restrict__ x, const float* __restrict__ w,
                           float* __restrict__ s, K32 pk, K16 rk) {
  constexpr int XR = 2 * (WT - 1) + KK;
  constexpr int TW = 4 * WT;                 // wo span per block (4 waves)
  constexpr int GROUPS = (WOUT + TW - 1) / TW;
  constexpr int NROW = COUT * TW;
  __shared__ float lds[NROW * 51];
  const int tid = threadIdx.x;
  const int wave = tid >> 6;
  const int lane = tid & 63;
  const int group = blockIdx.x % GROUPS;
  const int rest = blockIdx.x / GROUPS;
  const int ho = rest % HOUT;
  const int n = rest / HOUT;
  const int wo0 = group * TW + wave * WT;
  const int tt = lane < 50 ? lane : 49;

  float acc[COUT][WT] = {};
  for (int c = 0; c < CIN; ++c) {
#pragma unroll
    for (int kh = 0; kh < KK; ++kh) {
      const int hi = 2 * ho + kh - 1;
      if ((unsigned)hi >= (unsigned)HIN) continue;   // zero padding
      float xr[XR];
#pragma unroll
      for (int i = 0; i < XR; ++i) {
        const int wi = 2 * wo0 - 1 + i;
        xr[i] = ((unsigned)wi < (unsigned)WIN)
                    ? x[(((size_t)(n * CIN + c) * HIN + hi) * WIN + wi) * 50 + tt]
                    : 0.f;
      }
#pragma unroll
      for (int co = 0; co < COUT; ++co)
#pragma unroll
        for (int kw = 0; kw < KK; ++kw) {
          const float wv = w[((co * CIN + c) * KK + kh) * KK + kw];
#pragma unroll
          for (int wl = 0; wl < WT; ++wl)
            acc[co][wl] += xr[2 * wl + kw] * wv;
        }
    }
  }

  if (lane < 50) {
#pragma unroll
    for (int co = 0; co < COUT; ++co)
#pragma unroll
      for (int wl = 0; wl < WT; ++wl)
        lds[(co * TW + wave * WT + wl) * 51 + lane] = acc[co][wl];
  }
  __syncthreads();
  // ---- FIR = psp (commuted past conv): 2 threads/row ----
  {
    const int r = tid % NROW;
    const int part = tid / NROW;
    const int wol = r % TW;
    const bool act = (part < 2) && (group * TW + wol < WOUT);
    float xs[50];
    if (act) {
      if (part == 0) {
#pragma unroll
        for (int t = 0; t < 25; ++t) xs[t] = lds[r * 51 + t];
      } else {
#pragma unroll
        for (int t = 0; t < 50; ++t) xs[t] = lds[r * 51 + t];
      }
    }
    __syncthreads();
    if (act) {
      if (part == 0) {
#pragma unroll
        for (int t = 0; t < 25; ++t) {
          float a = 0.f;
#pragma unroll
          for (int k = 31; k >= 0; --k)
            if (t - k >= 0) a += xs[t - k] * pk.k[k];
          lds[r * 51 + t] = a;
        }
      } else {
#pragma unroll
        for (int t = 25; t < 50; ++t) {
          float a = 0.f;
#pragma unroll
          for (int k = 31; k >= 0; --k)
            if (t - k >= 0) a += xs[t - k] * pk.k[k];
          lds[r * 51 + t] = a;
        }
      }
    }
  }
  __syncthreads();
  // spike along t, one thread per output row, direct float2 store from regs
  if (tid < NROW) {
    const int co = tid / TW;
    const int wol = tid - co * TW;
    const int wo = group * TW + wol;
    if (wo < WOUT) {
      float* orow = s + (((size_t)(n * COUT + co) * HOUT + ho) * WOUT + wo) * 50;
      float buf[16];
#pragma unroll
      for (int j = 0; j < 16; ++j) buf[j] = 0.f;
      float prev = 0.f;
#pragma unroll
      for (int t = 0; t < 50; ++t) {
        float v = lds[tid * 51 + t] + buf[t & 15];
        buf[t & 15] = 0.f;
        float sp = 0.f;
        if (v >= THETA) {
          sp = 1.f;
#pragma unroll
          for (int j = 0; j < 16; ++j) buf[(t + 1 + j) & 15] += rk.k[j];
        }
        if (t & 1) *(float2*)(orow + t - 1) = make_float2(prev, sp);
        else prev = sp;
      }
    }
  }
}

// ====== fc + psp(commuted) + final spike (verified) ======
__global__ __launch_bounds__(512)
void fc_fir_spike_kernel(const float* __restrict__ w, const float* __restrict__ s,
                         float* __restrict__ out, K32 pk, K16 rk) {
  __shared__ float lds[8 * 51];
  const int tid = threadIdx.x;
  const int wave = tid >> 6, lane = tid & 63;
  const int o = wave & 1, n = wave >> 1;
  const int tt = lane < 50 ? lane : 49;
  const float* wrow = w + (size_t)o * 2048;
  const float* ub = s + (size_t)n * 2048 * 50;
  float acc = 0.f;
#pragma unroll 32
  for (int i = 0; i < 2048; ++i) acc += wrow[i] * ub[(size_t)i * 50 + tt];
  if (lane < 50) lds[wave * 51 + lane] = acc;
  __syncthreads();
  // ---- FIR = psp6 (commuted past einsum): 2 threads/row, in place ----
  {
    const int r = tid & 7;
    const int part = tid >> 3;      // only part<2 active
    const bool act = part < 2;
    float xs[50];
    if (act) {
      if (part == 0) {
#pragma unroll
        for (int t = 0; t < 25; ++t) xs[t] = lds[r * 51 + t];
      } else {
#pragma unroll
        for (int t = 0; t < 50; ++t) xs[t] = lds[r * 51 + t];
      }
    }
    __syncthreads();
    if (act) {
      if (part == 0) {
#pragma unroll
        for (int t = 0; t < 25; ++t) {
          float a = 0.f;
#pragma unroll
          for (int k = 31; k >= 0; --k)
            if (t - k >= 0) a += xs[t - k] * pk.k[k];
          lds[r * 51 + t] = a;
        }
      } else {
#pragma unroll
        for (int t = 25; t < 50; ++t) {
          float a = 0.f;
#pragma unroll
          for (int k = 31; k >= 0; --k)
            if (t - k >= 0) a += xs[t - k] * pk.k[k];
          lds[r * 51 + t] = a;
        }
      }
    }
  }
  __syncthreads();
  if (tid < 8) {
    float buf[16];
#pragma unroll
    for (int j = 0; j < 16; ++j) buf[j] = 0.f;
#pragma unroll
    for (int t = 0; t < 50; ++t) {
      float v = lds[tid * 51 + t] + buf[t & 15];
      buf[t & 15] = 0.f;
      float sp = 0.f;
      if (v >= THETA) {
        sp = 1.f;
#pragma unroll
        for (int j = 0; j < 16; ++j) buf[(t + 1 + j) & 15] += rk.k[j];
      }
      out[tid * 50 + t] = sp;
    }
  }
}

extern "C" void kernel_launch(void* const* d_in, const int* in_sizes, int n_in,
                              void* d_out, int out_size, void* d_ws, size_t ws_size,
                              hipStream_t stream) {
  const float* xin = (const float*)d_in[0];  // [4,2,256,256,50] raw binary spikes
  const float* w1  = (const float*)d_in[1];  // [8,2,5,5]
  const float* w2  = (const float*)d_in[2];  // [16,8,3,3]
  const float* w3  = (const float*)d_in[3];  // [32,16,3,3]
  const float* wfc = (const float*)d_in[4];  // [2,32,8,8]
  float* out = (float*)d_out;                // [4,2,1,1,50]

  float* R0 = (float*)d_ws;                  // 26,214,400 floats
  float* R1 = R0 + 26214400;

  K32 pk;
  for (int k = 0; k < 32; ++k)
    pk.k[k] = (float)(((double)k / 10.0) * exp(1.0 - (double)k / 10.0));
  K16 rk;
  for (int j = 0; j < 16; ++j) {
    const double tr = (double)(j + 1);
    rk.k[j] = (float)(-2.0 * 10.0 * tr * exp(1.0 - tr));
  }

  // 1. FULLY FUSED L1: conv1(raw x)+psp1+spike1+psp2+pool1+spike2: xin -> R1 = s2
  conv_pps_kernel<2, 8, 5, 256, 256, 127, 127, 63, 63>
      <<<4 * 63 * 16, 256, 0, stream>>>(xin, w1, R1, pk, rk);
  // 2. MERGED L2: conv2+psp3+spike3+pool2+psp4+spike4: R1 -> R0 = s4 [4,16,16,16,50]
  conv_pps2_kernel<8, 16, 3, 4, 2, 63, 63, 32, 32, 16, 16>
      <<<4 * 16 * 8, 256, 0, stream>>>(R1, w2, R0, pk, rk);
  // 3. FUSED conv3+psp5+spike5: R0 -> R1 = s5 [4,32,8,8,50]
  conv_fir_spike_kernel<16, 32, 3, 1, 16, 16, 8, 8>
      <<<4 * 8 * 2, 256, 0, stream>>>(R0, w3, R1, pk, rk);
  // 4. FUSED fc+psp6+final spike: R1 -> out
  fc_fir_spike_kernel<<<1, 512, 0, stream>>>(wfc, R1, out, pk, rk);
}

// Round 6
// 461.393 us; speedup vs baseline: 1.2651x; 1.0073x over previous
//
#include <hip/hip_runtime.h>
#include <cmath>

struct K32 { float k[32]; };
struct K16 { float k[16]; };

#define THETA 10.0f

// ====== L1 FULLY FUSED (R5-proven + R6 sparse-skip): conv1(raw x) + psp1 +
//        spike1 + psp2 + pool1 + spike2  ->  s2  ======
// R6: conv FMA loop restructured i-major with wave-uniform __any(xr[i]!=0)
// skip. Input is the raw binary spike train (~2% rate): P(50-t row all
// zero) ~= 0.98^50 ~= 36%, and each skip drops the whole co x (wl,kw) FMA
// block for that input column. Accumulation order per acc[co][wl] is still
// kw-ascending for fixed (c,kh) (i = 2*wl+kw ascending <=> kw ascending),
// so the sum is bit-identical; skipped terms are exact +0*w adds which can
// only perturb zero-sign, and all global outputs are spike maps.
template <int CIN, int COUT, int KK, int HIN, int WIN, int S1H, int S1W,
          int S2H, int S2W>
__global__ __launch_bounds__(256)
void conv_pps_kernel(const float* __restrict__ x, const float* __restrict__ w,
                     float* __restrict__ s2out, K32 pk, K16 rk) {
  constexpr int WT = 4;                       // s1-wo per wave
  constexpr int SW = 8;                       // s1-wo per block
  constexpr int XR = 2 * (WT - 1) + KK;       // 11
  constexpr int GROUPS = (S1W + SW - 1) / SW; // 16
  constexpr int NROW = COUT * 2 * SW;         // 128
  constexpr int T0 = 39;                      // balanced part split
  __shared__ float lds[NROW * 51];            // 26 KB
  const int tid = threadIdx.x;
  const int wave = tid >> 6;
  const int lane = tid & 63;
  const int group = blockIdx.x % GROUPS;
  const int rest = blockIdx.x / GROUPS;
  const int hop = rest % S2H;                 // s2 ho
  const int n = rest / S2H;
  const int ho_off = wave & 1;
  const int wo_half = wave >> 1;
  const int ho = 2 * hop + ho_off;            // s1 ho
  const int wo0 = group * SW + wo_half * WT;
  const int tt = lane < 50 ? lane : 49;

  // ---- conv on RAW binary spikes, i-major with sparsity skip ----
  float acc[COUT][WT] = {};
  for (int c = 0; c < CIN; ++c) {
#pragma unroll
    for (int kh = 0; kh < KK; ++kh) {
      const int hi = 2 * ho + kh - 1;
      if ((unsigned)hi >= (unsigned)HIN) continue;   // zero padding
      float xr[XR];
#pragma unroll
      for (int i = 0; i < XR; ++i) {
        const int wi = 2 * wo0 - 1 + i;
        xr[i] = ((unsigned)wi < (unsigned)WIN)
                    ? x[(((size_t)(n * CIN + c) * HIN + hi) * WIN + wi) * 50 + tt]
                    : 0.f;
      }
#pragma unroll
      for (int i = 0; i < XR; ++i) {
        if (__any(xr[i] != 0.f)) {
#pragma unroll
          for (int co = 0; co < COUT; ++co)
#pragma unroll
            for (int wl = 0; wl < WT; ++wl)
#pragma unroll
              for (int kw = 0; kw < KK; ++kw)
                if (2 * wl + kw == i)          // compile-time after unroll
                  acc[co][wl] += xr[i] * w[((co * CIN + c) * KK + kh) * KK + kw];
        }
      }
    }
  }
  // ---- transpose: LDS row = co*16 + ho_off*8 + wol ----
  if (lane < 50) {
#pragma unroll
    for (int co = 0; co < COUT; ++co)
#pragma unroll
      for (int wl = 0; wl < WT; ++wl)
        lds[((co * 2 + ho_off) * SW + wo_half * WT + wl) * 51 + lane] = acc[co][wl];
  }
  __syncthreads();
  // ---- FUSED FIR1(psp1) + spike1 + FIR2(psp2): 2 threads/row, registers ----
  {
    const int r = tid & (NROW - 1);
    const int part = tid >> 7;                // 0: y[0..T0), 1: y[T0..49]
    const int wol = r & (SW - 1);
    const bool act = (group * SW + wol) < S1W;
    float xs[50];                             // conv output c
    if (act) {
      if (part == 0) {
#pragma unroll
        for (int t = 0; t < T0; ++t) xs[t] = lds[r * 51 + t];
      } else {
#pragma unroll
        for (int t = 0; t < 50; ++t) xs[t] = lds[r * 51 + t];
      }
    }
    __syncthreads();                          // all reads done before any FIR write
    if (act) {
      if (part == 0) {
        float us[T0];
#pragma unroll
        for (int t = 0; t < 32; ++t) {        // FIR1: u[0..31] (guarded taps)
          float a = 0.f;
#pragma unroll
          for (int k = 31; k >= 0; --k)
            if (t - k >= 0) a += xs[t - k] * pk.k[k];
          us[t] = a;
        }
#pragma unroll
        for (int t = 32; t < T0; ++t) {       // FIR1: u[32..38] (all taps valid)
          float a = 0.f;
#pragma unroll
          for (int k = 31; k >= 0; --k)
            a += xs[t - k] * pk.k[k];
          us[t] = a;
        }
        float buf[16];
#pragma unroll
        for (int j = 0; j < 16; ++j) buf[j] = 0.f;
#pragma unroll
        for (int t = 0; t < T0; ++t) {        // spike1 in regs, overwrite us
          float v = us[t] + buf[t & 15];
          buf[t & 15] = 0.f;
          float sp = 0.f;
          if (v >= THETA) {
            sp = 1.f;
#pragma unroll
            for (int j = 0; j < 16; ++j) buf[(t + 1 + j) & 15] += rk.k[j];
          }
          us[t] = sp;
        }
#pragma unroll
        for (int t = 0; t < 32; ++t) {        // FIR2: y[0..31] (guarded)
          float a = 0.f;
#pragma unroll
          for (int k = 31; k >= 0; --k)
            if (t - k >= 0) a += us[t - k] * pk.k[k];
          lds[r * 51 + t] = a;
        }
#pragma unroll
        for (int t = 32; t < T0; ++t) {       // FIR2: y[32..38] (all taps valid)
          float a = 0.f;
#pragma unroll
          for (int k = 31; k >= 0; --k)
            a += us[t - k] * pk.k[k];
          lds[r * 51 + t] = a;
        }
      } else {
        float us[50];
#pragma unroll
        for (int t = 0; t < 32; ++t) {        // FIR1 full prefix (guarded)
          float a = 0.f;
#pragma unroll
          for (int k = 31; k >= 0; --k)
            if (t - k >= 0) a += xs[t - k] * pk.k[k];
          us[t] = a;
        }
#pragma unroll
        for (int t = 32; t < 50; ++t) {       // FIR1 (all taps valid)
          float a = 0.f;
#pragma unroll
          for (int k = 31; k >= 0; --k)
            a += xs[t - k] * pk.k[k];
          us[t] = a;
        }
        float buf[16];
#pragma unroll
        for (int j = 0; j < 16; ++j) buf[j] = 0.f;
#pragma unroll
        for (int t = 0; t < 50; ++t) {        // spike1 full row, overwrite us
          float v = us[t] + buf[t & 15];
          buf[t & 15] = 0.f;
          float sp = 0.f;
          if (v >= THETA) {
            sp = 1.f;
#pragma unroll
            for (int j = 0; j < 16; ++j) buf[(t + 1 + j) & 15] += rk.k[j];
          }
          us[t] = sp;
        }
#pragma unroll
        for (int t = T0; t < 50; ++t) {       // FIR2: y[39..49] (all taps valid)
          float a = 0.f;
#pragma unroll
          for (int k = 31; k >= 0; --k)
            a += us[t - k] * pk.k[k];
          lds[r * 51 + t] = a;
        }
      }
    }
  }
  __syncthreads();
  // ---- pool ((h0w0+h0w1)+h1w0)+h1w1 * 2.75 -> spike -> direct store ----
  if (tid < COUT * (SW / 2)) {                // 32 threads
    const int co = tid / (SW / 2);
    const int wpl = tid % (SW / 2);
    const int wop = group * (SW / 2) + wpl;   // s2 wo
    if (wop < S2W) {
      const int r00 = (co * 16 + 2 * wpl) * 51;
      const int r01 = (co * 16 + 2 * wpl + 1) * 51;
      const int r10 = (co * 16 + 8 + 2 * wpl) * 51;
      const int r11 = (co * 16 + 8 + 2 * wpl + 1) * 51;
      float* orow = s2out + (((size_t)(n * COUT + co) * S2H + hop) * S2W + wop) * 50;
      float buf[16];
#pragma unroll
      for (int j = 0; j < 16; ++j) buf[j] = 0.f;
      float prev = 0.f;
#pragma unroll
      for (int t = 0; t < 50; ++t) {
        const float u0 = (((lds[r00 + t] + lds[r01 + t]) + lds[r10 + t]) + lds[r11 + t]) * 2.75f;
        float v = u0 + buf[t & 15];
        buf[t & 15] = 0.f;
        float sp = 0.f;
        if (v >= THETA) {
          sp = 1.f;
#pragma unroll
          for (int j = 0; j < 16; ++j) buf[(t + 1 + j) & 15] += rk.k[j];
        }
        if (t & 1) *(float2*)(orow + t - 1) = make_float2(prev, sp);
        else prev = sp;
      }
    }
  }
}

// ====== L2 MERGED (R4-proven + R6 sparse-skip): conv2 + psp3 + spike3 +
//        pool2 + psp4 + spike4 ======
template <int CIN, int COUT, int KK, int SW, int WT, int HIN, int WIN,
          int S1H, int S1W, int S2H, int S2W>
__global__ __launch_bounds__(256)
void conv_pps2_kernel(const float* __restrict__ x, const float* __restrict__ w,
                      float* __restrict__ s2out, K32 pk, K16 rk) {
  constexpr int XR = 2 * (WT - 1) + KK;       // 5
  constexpr int GROUPS = (S1W + SW - 1) / SW; // 8
  constexpr int NROW = COUT * 2 * SW;         // 128
  constexpr int NROWP = COUT * (SW / 2);      // 32 pooled rows
  __shared__ float lds[NROW * 51];            // 26 KB
  const int tid = threadIdx.x;
  const int wave = tid >> 6;
  const int lane = tid & 63;
  const int group = blockIdx.x % GROUPS;
  const int rest = blockIdx.x / GROUPS;
  const int hop = rest % S2H;                 // s2 ho
  const int n = rest / S2H;
  const int ho_off = wave & 1;
  const int wo_half = wave >> 1;
  const int ho = 2 * hop + ho_off;            // s1 ho
  const int wo0 = group * SW + wo_half * WT;
  const int tt = lane < 50 ? lane : 49;

  // ---- conv on raw s2 spikes, i-major with sparsity skip ----
  float acc[COUT][WT] = {};
  for (int c = 0; c < CIN; ++c) {
#pragma unroll
    for (int kh = 0; kh < KK; ++kh) {
      const int hi = 2 * ho + kh - 1;
      if ((unsigned)hi >= (unsigned)HIN) continue;   // zero padding
      float xr[XR];
#pragma unroll
      for (int i = 0; i < XR; ++i) {
        const int wi = 2 * wo0 - 1 + i;
        xr[i] = ((unsigned)wi < (unsigned)WIN)
                    ? x[(((size_t)(n * CIN + c) * HIN + hi) * WIN + wi) * 50 + tt]
                    : 0.f;
      }
#pragma unroll
      for (int i = 0; i < XR; ++i) {
        if (__any(xr[i] != 0.f)) {
#pragma unroll
          for (int co = 0; co < COUT; ++co)
#pragma unroll
            for (int wl = 0; wl < WT; ++wl)
#pragma unroll
              for (int kw = 0; kw < KK; ++kw)
                if (2 * wl + kw == i)          // compile-time after unroll
                  acc[co][wl] += xr[i] * w[((co * CIN + c) * KK + kh) * KK + kw];
        }
      }
    }
  }
  // ---- transpose: LDS row = (co*2 + ho_off)*SW + wol ----
  if (lane < 50) {
#pragma unroll
    for (int co = 0; co < COUT; ++co)
#pragma unroll
      for (int wl = 0; wl < WT; ++wl)
        lds[((co * 2 + ho_off) * SW + wo_half * WT + wl) * 51 + lane] = acc[co][wl];
  }
  __syncthreads();
  // ---- FIR (psp3) on 128 conv rows: 2 thr/row, snapshot -> barrier -> in-place ----
  {
    const int r = tid & (NROW - 1);
    const int part = tid >> 7;                // 0: y[0..31], 1: y[32..49]
    float xs[50];
    if (part == 0) {
#pragma unroll
      for (int t = 0; t < 32; ++t) xs[t] = lds[r * 51 + t];
    } else {
#pragma unroll
      for (int t = 0; t < 50; ++t) xs[t] = lds[r * 51 + t];
    }
    __syncthreads();
    if (part == 0) {
#pragma unroll
      for (int t = 0; t < 32; ++t) {
        float a = 0.f;
#pragma unroll
        for (int k = 31; k >= 0; --k)
          if (t - k >= 0) a += xs[t - k] * pk.k[k];
        lds[r * 51 + t] = a;
      }
    } else {
#pragma unroll
      for (int t = 32; t < 50; ++t) {
        float a = 0.f;
#pragma unroll
        for (int k = 31; k >= 0; --k)
          a += xs[t - k] * pk.k[k];            // all taps valid for t >= 32
        lds[r * 51 + t] = a;
      }
    }
  }
  __syncthreads();
  // ---- spike3 per row (128 rows, in place) ----
  if (tid < NROW) {
    float buf[16];
#pragma unroll
    for (int j = 0; j < 16; ++j) buf[j] = 0.f;
#pragma unroll
    for (int t = 0; t < 50; ++t) {
      float v = lds[tid * 51 + t] + buf[t & 15];
      buf[t & 15] = 0.f;
      float sp = 0.f;
      if (v >= THETA) {
        sp = 1.f;
#pragma unroll
        for (int j = 0; j < 16; ++j) buf[(t + 1 + j) & 15] += rk.k[j];
      }
      lds[tid * 51 + t] = sp;
    }
  }
  __syncthreads();
  // ---- pool-sum + FIR (psp4) on 32 pooled rows: 2 thr/row ----
  {
    const int r = tid & (NROWP - 1);
    const int part = tid >> 5;                // 0..7, only part<2 active
    const bool act = part < 2;
    const int co = r / (SW / 2);
    const int wpl = r % (SW / 2);
    const int r00 = ((co * 2) * SW + 2 * wpl) * 51;
    const int r01 = r00 + 51;
    const int r10 = ((co * 2 + 1) * SW + 2 * wpl) * 51;
    const int r11 = r10 + 51;
    float xs[50];
    if (act) {
      if (part == 0) {
#pragma unroll
        for (int t = 0; t < 32; ++t)
          xs[t] = (((lds[r00 + t] + lds[r01 + t]) + lds[r10 + t]) + lds[r11 + t]) * 2.75f;
      } else {
#pragma unroll
        for (int t = 0; t < 50; ++t)
          xs[t] = (((lds[r00 + t] + lds[r01 + t]) + lds[r10 + t]) + lds[r11 + t]) * 2.75f;
      }
    }
    __syncthreads();
    if (act) {
      if (part == 0) {
#pragma unroll
        for (int t = 0; t < 32; ++t) {
          float a = 0.f;
#pragma unroll
          for (int k = 31; k >= 0; --k)
            if (t - k >= 0) a += xs[t - k] * pk.k[k];
          lds[r00 + t] = a;
        }
      } else {
#pragma unroll
        for (int t = 32; t < 50; ++t) {
          float a = 0.f;
#pragma unroll
          for (int k = 31; k >= 0; --k)
            a += xs[t - k] * pk.k[k];
          lds[r00 + t] = a;
        }
      }
    }
  }
  __syncthreads();
  // ---- spike4 -> direct store ----
  if (tid < NROWP) {
    const int co = tid / (SW / 2);
    const int wpl = tid % (SW / 2);
    const int wop = group * (SW / 2) + wpl;   // s2 wo
    if (wop < S2W) {
      const int r00 = ((co * 2) * SW + 2 * wpl) * 51;
      float* orow = s2out + (((size_t)(n * COUT + co) * S2H + hop) * S2W + wop) * 50;
      float buf[16];
#pragma unroll
      for (int j = 0; j < 16; ++j) buf[j] = 0.f;
      float prev = 0.f;
#pragma unroll
      for (int t = 0; t < 50; ++t) {
        float v = lds[r00 + t] + buf[t & 15];
        buf[t & 15] = 0.f;
        float sp = 0.f;
        if (v >= THETA) {
          sp = 1.f;
#pragma unroll
          for (int j = 0; j < 16; ++j) buf[(t + 1 + j) & 15] += rk.k[j];
        }
        if (t & 1) *(float2*)(orow + t - 1) = make_float2(prev, sp);
        else prev = sp;
      }
    }
  }
}

// ====== fused conv (stride2,pad1) + psp(commuted) + spike (verified, L3 only) ======
template <int CIN, int COUT, int KK, int WT, int HIN, int WIN, int HOUT, int WOUT>
__global__ __launch_bounds__(256)
void conv_fir_spike_kernel(const float* __restrict__ x, const float* __restrict__ w,
                           float* __restrict__ s, K32 pk, K16 rk) {
  constexpr int XR = 2 * (WT - 1) + KK;
  constexpr int TW = 4 * WT;                 // wo span per block (4 waves)
  constexpr int GROUPS = (WOUT + TW - 1) / TW;
  constexpr int NROW = COUT * TW;
  __shared__ float lds[NROW * 51];
  const int tid = threadIdx.x;
  const int wave = tid >> 6;
  const int lane = tid & 63;
  const int group = blockIdx.x % GROUPS;
  const int rest = blockIdx.x / GROUPS;
  const int ho = rest % HOUT;
  const int n = rest / HOUT;
  const int wo0 = group * TW + wave * WT;
  const int tt = lane < 50 ? lane : 49;

  float acc[COUT][WT] = {};
  for (int c = 0; c < CIN; ++c) {
#pragma unroll
    for (int kh = 0; kh < KK; ++kh) {
      const int hi = 2 * ho + kh - 1;
      if ((unsigned)hi >= (unsigned)HIN) continue;   // zero padding
      float xr[XR];
#pragma unroll
      for (int i = 0; i < XR; ++i) {
        const int wi = 2 * wo0 - 1 + i;
        xr[i] = ((unsigned)wi < (unsigned)WIN)
                    ? x[(((size_t)(n * CIN + c) * HIN + hi) * WIN + wi) * 50 + tt]
                    : 0.f;
      }
#pragma unroll
      for (int co = 0; co < COUT; ++co)
#pragma unroll
        for (int kw = 0; kw < KK; ++kw) {
          const float wv = w[((co * CIN + c) * KK + kh) * KK + kw];
#pragma unroll
          for (int wl = 0; wl < WT; ++wl)
            acc[co][wl] += xr[2 * wl + kw] * wv;
        }
    }
  }

  if (lane < 50) {
#pragma unroll
    for (int co = 0; co < COUT; ++co)
#pragma unroll
      for (int wl = 0; wl < WT; ++wl)
        lds[(co * TW + wave * WT + wl) * 51 + lane] = acc[co][wl];
  }
  __syncthreads();
  // ---- FIR = psp (commuted past conv): 2 threads/row ----
  {
    const int r = tid % NROW;
    const int part = tid / NROW;
    const int wol = r % TW;
    const bool act = (part < 2) && (group * TW + wol < WOUT);
    float xs[50];
    if (act) {
      if (part == 0) {
#pragma unroll
        for (int t = 0; t < 25; ++t) xs[t] = lds[r * 51 + t];
      } else {
#pragma unroll
        for (int t = 0; t < 50; ++t) xs[t] = lds[r * 51 + t];
      }
    }
    __syncthreads();
    if (act) {
      if (part == 0) {
#pragma unroll
        for (int t = 0; t < 25; ++t) {
          float a = 0.f;
#pragma unroll
          for (int k = 31; k >= 0; --k)
            if (t - k >= 0) a += xs[t - k] * pk.k[k];
          lds[r * 51 + t] = a;
        }
      } else {
#pragma unroll
        for (int t = 25; t < 50; ++t) {
          float a = 0.f;
#pragma unroll
          for (int k = 31; k >= 0; --k)
            if (t - k >= 0) a += xs[t - k] * pk.k[k];
          lds[r * 51 + t] = a;
        }
      }
    }
  }
  __syncthreads();
  // spike along t, one thread per output row, direct float2 store from regs
  if (tid < NROW) {
    const int co = tid / TW;
    const int wol = tid - co * TW;
    const int wo = group * TW + wol;
    if (wo < WOUT) {
      float* orow = s + (((size_t)(n * COUT + co) * HOUT + ho) * WOUT + wo) * 50;
      float buf[16];
#pragma unroll
      for (int j = 0; j < 16; ++j) buf[j] = 0.f;
      float prev = 0.f;
#pragma unroll
      for (int t = 0; t < 50; ++t) {
        float v = lds[tid * 51 + t] + buf[t & 15];
        buf[t & 15] = 0.f;
        float sp = 0.f;
        if (v >= THETA) {
          sp = 1.f;
#pragma unroll
          for (int j = 0; j < 16; ++j) buf[(t + 1 + j) & 15] += rk.k[j];
        }
        if (t & 1) *(float2*)(orow + t - 1) = make_float2(prev, sp);
        else prev = sp;
      }
    }
  }
}

// ====== fc + psp(commuted) + final spike (verified) ======
__global__ __launch_bounds__(512)
void fc_fir_spike_kernel(const float* __restrict__ w, const float* __restrict__ s,
                         float* __restrict__ out, K32 pk, K16 rk) {
  __shared__ float lds[8 * 51];
  const int tid = threadIdx.x;
  const int wave = tid >> 6, lane = tid & 63;
  const int o = wave & 1, n = wave >> 1;
  const int tt = lane < 50 ? lane : 49;
  const float* wrow = w + (size_t)o * 2048;
  const float* ub = s + (size_t)n * 2048 * 50;
  float acc = 0.f;
#pragma unroll 32
  for (int i = 0; i < 2048; ++i) acc += wrow[i] * ub[(size_t)i * 50 + tt];
  if (lane < 50) lds[wave * 51 + lane] = acc;
  __syncthreads();
  // ---- FIR = psp6 (commuted past einsum): 2 threads/row, in place ----
  {
    const int r = tid & 7;
    const int part = tid >> 3;      // only part<2 active
    const bool act = part < 2;
    float xs[50];
    if (act) {
      if (part == 0) {
#pragma unroll
        for (int t = 0; t < 25; ++t) xs[t] = lds[r * 51 + t];
      } else {
#pragma unroll
        for (int t = 0; t < 50; ++t) xs[t] = lds[r * 51 + t];
      }
    }
    __syncthreads();
    if (act) {
      if (part == 0) {
#pragma unroll
        for (int t = 0; t < 25; ++t) {
          float a = 0.f;
#pragma unroll
          for (int k = 31; k >= 0; --k)
            if (t - k >= 0) a += xs[t - k] * pk.k[k];
          lds[r * 51 + t] = a;
        }
      } else {
#pragma unroll
        for (int t = 25; t < 50; ++t) {
          float a = 0.f;
#pragma unroll
          for (int k = 31; k >= 0; --k)
            if (t - k >= 0) a += xs[t - k] * pk.k[k];
          lds[r * 51 + t] = a;
        }
      }
    }
  }
  __syncthreads();
  if (tid < 8) {
    float buf[16];
#pragma unroll
    for (int j = 0; j < 16; ++j) buf[j] = 0.f;
#pragma unroll
    for (int t = 0; t < 50; ++t) {
      float v = lds[tid * 51 + t] + buf[t & 15];
      buf[t & 15] = 0.f;
      float sp = 0.f;
      if (v >= THETA) {
        sp = 1.f;
#pragma unroll
        for (int j = 0; j < 16; ++j) buf[(t + 1 + j) & 15] += rk.k[j];
      }
      out[tid * 50 + t] = sp;
    }
  }
}

extern "C" void kernel_launch(void* const* d_in, const int* in_sizes, int n_in,
                              void* d_out, int out_size, void* d_ws, size_t ws_size,
                              hipStream_t stream) {
  const float* xin = (const float*)d_in[0];  // [4,2,256,256,50] raw binary spikes
  const float* w1  = (const float*)d_in[1];  // [8,2,5,5]
  const float* w2  = (const float*)d_in[2];  // [16,8,3,3]
  const float* w3  = (const float*)d_in[3];  // [32,16,3,3]
  const float* wfc = (const float*)d_in[4];  // [2,32,8,8]
  float* out = (float*)d_out;                // [4,2,1,1,50]

  float* R0 = (float*)d_ws;                  // 26,214,400 floats
  float* R1 = R0 + 26214400;

  K32 pk;
  for (int k = 0; k < 32; ++k)
    pk.k[k] = (float)(((double)k / 10.0) * exp(1.0 - (double)k / 10.0));
  K16 rk;
  for (int j = 0; j < 16; ++j) {
    const double tr = (double)(j + 1);
    rk.k[j] = (float)(-2.0 * 10.0 * tr * exp(1.0 - tr));
  }

  // 1. FULLY FUSED L1: conv1(raw x)+psp1+spike1+psp2+pool1+spike2: xin -> R1 = s2
  conv_pps_kernel<2, 8, 5, 256, 256, 127, 127, 63, 63>
      <<<4 * 63 * 16, 256, 0, stream>>>(xin, w1, R1, pk, rk);
  // 2. MERGED L2: conv2+psp3+spike3+pool2+psp4+spike4: R1 -> R0 = s4 [4,16,16,16,50]
  conv_pps2_kernel<8, 16, 3, 4, 2, 63, 63, 32, 32, 16, 16>
      <<<4 * 16 * 8, 256, 0, stream>>>(R1, w2, R0, pk, rk);
  // 3. FUSED conv3+psp5+spike5: R0 -> R1 = s5 [4,32,8,8,50]
  conv_fir_spike_kernel<16, 32, 3, 1, 16, 16, 8, 8>
      <<<4 * 8 * 2, 256, 0, stream>>>(R0, w3, R1, pk, rk);
  // 4. FUSED fc+psp6+final spike: R1 -> out
  fc_fir_spike_kernel<<<1, 512, 0, stream>>>(wfc, R1, out, pk, rk);
}